// Round 6
// baseline (444.758 us; speedup 1.0000x reference)
//
#include <hip/hip_runtime.h>

#define B_ 2048
#define T_ 256
#define NV_ 32
#define H_ 64
#define L_ 32
#define OH_ 64
#define NSTEP 16
#define DEPTH 3

typedef _Float16 f16x8 __attribute__((ext_vector_type(8)));
typedef _Float16 f16x4 __attribute__((ext_vector_type(4)));
typedef float f32x4 __attribute__((ext_vector_type(4)));

#define MFMA16(a, b, c) __builtin_amdgcn_mfma_f32_16x16x32_f16((a), (b), (c), 0, 0, 0)

__device__ __forceinline__ float rcp_(float x) { return __builtin_amdgcn_rcpf(x); }
__device__ __forceinline__ float sigm(float x) { return rcp_(1.0f + __expf(-x)); }
__device__ __forceinline__ float tanh_(float x) { return 2.0f * rcp_(1.0f + __expf(-2.0f * x)) - 1.0f; }

__device__ __forceinline__ f16x8 pack8(f32x4 a, f32x4 b) {
    f16x8 r;
    r[0] = (_Float16)a[0]; r[1] = (_Float16)a[1]; r[2] = (_Float16)a[2]; r[3] = (_Float16)a[3];
    r[4] = (_Float16)b[0]; r[5] = (_Float16)b[1]; r[6] = (_Float16)b[2]; r[7] = (_Float16)b[3];
    return r;
}

// ---------------------------------------------------------------------------
// GRU encoder: 128 blocks x 1 wave. Each wave owns a 16-batch tile and the
// ENTIRE recurrence: no LDS, no barriers, no cross-wave traffic in the loop.
//
// Key trick: weight rows are loaded in permuted order
//   sigma(16*ft + 4*g4 + r) = 8*g4 + 4*(ft&1) + r + 32*(ft>>1)
// so the MFMA C-tile slots (ft, r) at lane (c,g4) hold exactly the h features
// (k = 32*kt + 8*g4 + i, batch c) that the SAME lane needs as its B-fragment
// for the next step's h-MFMAs. The h state never leaves registers: the
// C->B transpose that previously cost an LDS round-trip + sync per step
// (~1700 cy, the measured floor of rounds 2-5) becomes 2 pack8 calls.
// sigma is a bijection on 0..63, applied identically to r/z/n rows of
// W_ih, W_hh and biases, so the math is exact.
// ---------------------------------------------------------------------------
__global__ __launch_bounds__(64) void gru_kernel(
    const float* __restrict__ values, const float* __restrict__ mask,
    const int* __restrict__ seql, const float* __restrict__ eps,
    const float* __restrict__ W_ih, const float* __restrict__ W_hh,
    const float* __restrict__ b_ih, const float* __restrict__ b_hh,
    const float* __restrict__ W_z0, const float* __restrict__ b_z0,
    float* __restrict__ z0ws, float* __restrict__ parts)
{
    const int l  = threadIdx.x;
    const int c  = l & 15;
    const int g4 = l >> 4;
    const int b0 = blockIdx.x * 16;

    // Weight A-fragments, permuted rows. lane (c,g4), tile ft, frag kt holds
    // W[gate*64 + sigma(16ft + c)][kt*32 + 8g4 .. +8]
    f16x8 wihR[4][2], wihZ[4][2], wihN[4][2];
    f16x8 whhR[4][2], whhZ[4][2], whhN[4][2];
#pragma unroll
    for (int ft = 0; ft < 4; ++ft) {
        const int sig = 8 * (c >> 2) + (c & 3) + 4 * (ft & 1) + 32 * (ft >> 1);
#pragma unroll
        for (int kt = 0; kt < 2; ++kt) {
            const float* pR = W_ih + (0 * 64 + sig) * 64 + kt * 32 + g4 * 8;
            const float* pZ = W_ih + (1 * 64 + sig) * 64 + kt * 32 + g4 * 8;
            const float* pN = W_ih + (2 * 64 + sig) * 64 + kt * 32 + g4 * 8;
            wihR[ft][kt] = pack8(*(const f32x4*)pR, *(const f32x4*)(pR + 4));
            wihZ[ft][kt] = pack8(*(const f32x4*)pZ, *(const f32x4*)(pZ + 4));
            wihN[ft][kt] = pack8(*(const f32x4*)pN, *(const f32x4*)(pN + 4));
            const float* qR = W_hh + (0 * 64 + sig) * 64 + kt * 32 + g4 * 8;
            const float* qZ = W_hh + (1 * 64 + sig) * 64 + kt * 32 + g4 * 8;
            const float* qN = W_hh + (2 * 64 + sig) * 64 + kt * 32 + g4 * 8;
            whhR[ft][kt] = pack8(*(const f32x4*)qR, *(const f32x4*)(qR + 4));
            whhZ[ft][kt] = pack8(*(const f32x4*)qZ, *(const f32x4*)(qZ + 4));
            whhN[ft][kt] = pack8(*(const f32x4*)qN, *(const f32x4*)(qN + 4));
        }
    }

    // Biases per C slot (ft, r): feature fb = sigma at (ft, g4, r)
    f32x4 bRq[4], bZq[4], bNXq[4], bNHq[4];
#pragma unroll
    for (int ft = 0; ft < 4; ++ft) {
#pragma unroll
        for (int r = 0; r < 4; ++r) {
            const int fb = 8 * g4 + 4 * (ft & 1) + r + 32 * (ft >> 1);
            bRq[ft][r]  = b_ih[fb]       + b_hh[fb];
            bZq[ft][r]  = b_ih[64 + fb]  + b_hh[64 + fb];
            bNXq[ft][r] = b_ih[128 + fb];
            bNHq[ft][r] = b_hh[128 + fb];
        }
    }

    const int sl_c = seql[b0 + c];
    const int tmax = seql[b0];       // sorted descending -> block max

    f32x4 hp4[4] = {{0.f,0.f,0.f,0.f},{0.f,0.f,0.f,0.f},
                    {0.f,0.f,0.f,0.f},{0.f,0.f,0.f,0.f}};

    const float* vrow = values + (size_t)(b0 + c) * T_ * NV_ + g4 * 8;
    const float* mrow = mask   + (size_t)(b0 + c) * T_ * NV_ + g4 * 8;

    // depth-3 register prefetch, named sets (static indexing)
#define DECLSET(S) f32x4 S##v0, S##v1, S##m0, S##m1
    DECLSET(A); DECLSET(B); DECLSET(C);
#define FILLSET(S, tc) do {                                                  \
        const int tt_ = ((tc) < tmax) ? (tc) : 0;                            \
        const float* vp_ = vrow + (T_ - 1 - tt_) * NV_;                      \
        const float* mp_ = mrow + (T_ - 1 - tt_) * NV_;                      \
        S##v0 = *(const f32x4*)vp_; S##v1 = *(const f32x4*)(vp_ + 4);        \
        S##m0 = *(const f32x4*)mp_; S##m1 = *(const f32x4*)(mp_ + 4);        \
    } while (0)
    FILLSET(A, 0); FILLSET(B, 1); FILLSET(C, 2);

#define GSTEP(S, tc) do {                                                    \
        f16x8 xa0 = pack8(S##v0, S##v1);                                     \
        f16x8 xa1 = pack8(S##m0, S##m1);                                     \
        FILLSET(S, (tc) + DEPTH);                                            \
        f16x8 hb0 = pack8(hp4[0], hp4[1]);                                   \
        f16x8 hb1 = pack8(hp4[2], hp4[3]);                                   \
        f32x4 aR[4], aZ[4], aNX[4], aNH[4];                                  \
        _Pragma("unroll")                                                    \
        for (int ft = 0; ft < 4; ++ft) {                                     \
            aR[ft]  = MFMA16(wihR[ft][0], xa0, bRq[ft]);                     \
            aZ[ft]  = MFMA16(wihZ[ft][0], xa0, bZq[ft]);                     \
            aNX[ft] = MFMA16(wihN[ft][0], xa0, bNXq[ft]);                    \
            aR[ft]  = MFMA16(wihR[ft][1], xa1, aR[ft]);                      \
            aZ[ft]  = MFMA16(wihZ[ft][1], xa1, aZ[ft]);                      \
            aNX[ft] = MFMA16(wihN[ft][1], xa1, aNX[ft]);                     \
            aNH[ft] = MFMA16(whhN[ft][0], hb0, bNHq[ft]);                    \
            aR[ft]  = MFMA16(whhR[ft][0], hb0, aR[ft]);                      \
            aZ[ft]  = MFMA16(whhZ[ft][0], hb0, aZ[ft]);                      \
            aNH[ft] = MFMA16(whhN[ft][1], hb1, aNH[ft]);                     \
            aR[ft]  = MFMA16(whhR[ft][1], hb1, aR[ft]);                      \
            aZ[ft]  = MFMA16(whhZ[ft][1], hb1, aZ[ft]);                      \
        }                                                                    \
        const bool act = ((tc) < sl_c);                                      \
        _Pragma("unroll")                                                    \
        for (int ft = 0; ft < 4; ++ft) {                                     \
            _Pragma("unroll")                                                \
            for (int r = 0; r < 4; ++r) {                                    \
                float rr   = sigm(aR[ft][r]);                                \
                float zz   = sigm(aZ[ft][r]);                                \
                float nn   = tanh_(aNX[ft][r] + rr * aNH[ft][r]);            \
                float hnew = nn + zz * (hp4[ft][r] - nn);                    \
                if (act) hp4[ft][r] = hnew;                                  \
            }                                                                \
        }                                                                    \
    } while (0)

    int t = 0;
    while (true) {
        GSTEP(A, t); if (++t >= tmax) break;
        GSTEP(B, t); if (++t >= tmax) break;
        GSTEP(C, t); if (++t >= tmax) break;
    }

    // Epilogue: z0p = W_z0 * h^T + b_z0 (natural row order), all lane-local.
    f16x8 hb0 = pack8(hp4[0], hp4[1]);
    f16x8 hb1 = pack8(hp4[2], hp4[3]);
    f32x4 az[4];
#pragma unroll
    for (int ft = 0; ft < 4; ++ft) {
        f32x4 bz;
#pragma unroll
        for (int r = 0; r < 4; ++r) bz[r] = b_z0[ft * 16 + g4 * 4 + r];
        const float* p0 = W_z0 + (ft * 16 + c) * 64 + g4 * 8;
        const float* p1 = W_z0 + (ft * 16 + c) * 64 + 32 + g4 * 8;
        f16x8 a0 = pack8(*(const f32x4*)p0, *(const f32x4*)(p0 + 4));
        f16x8 a1 = pack8(*(const f32x4*)p1, *(const f32x4*)(p1 + 4));
        az[ft] = MFMA16(a0, hb0, bz);
        az[ft] = MFMA16(a1, hb1, az[ft]);
    }
    // az[ft] reg r = z0p[16ft + 4g4 + r][batch c]; mean = rows 0..31 (ft 0,1),
    // logvar = rows 32..63 (ft 2,3) -> pairs (0,2) and (1,3) are lane-local.
    float kls = 0.0f;
#pragma unroll
    for (int pi = 0; pi < 2; ++pi) {
        f32x4 m = az[pi];
        f32x4 v = az[pi + 2];
        const int j0 = pi * 16 + g4 * 4;
        f32x4 e = *(const f32x4*)(eps + (size_t)(b0 + c) * L_ + j0);
        f32x4 zo;
#pragma unroll
        for (int r = 0; r < 4; ++r) {
            float s = __expf(0.5f * v[r]);
            zo[r] = m[r] + e[r] * s;
            kls += 1.0f + v[r] - m[r] * m[r] - s * s;
        }
        *(f32x4*)(z0ws + (size_t)(b0 + c) * L_ + j0) = zo;
    }
#pragma unroll
    for (int off = 32; off >= 1; off >>= 1) kls += __shfl_down(kls, off);
    if (l == 0) parts[blockIdx.x] = kls;
}

// ---------------------------------------------------------------------------
// ODE (RK4, NSTEP fixed steps over [0,48]) + decoder. One wave / 16 rows.
// ---------------------------------------------------------------------------
__global__ __launch_bounds__(64) void ode_kernel(
    const float* __restrict__ z0ws,
    const float* __restrict__ oW1, const float* __restrict__ ob1,
    const float* __restrict__ oW2, const float* __restrict__ ob2,
    const float* __restrict__ oW3, const float* __restrict__ ob3,
    const float* __restrict__ dW1, const float* __restrict__ db1,
    const float* __restrict__ dW2, const float* __restrict__ db2,
    float* __restrict__ out)
{
    const int l  = threadIdx.x;
    const int c  = l & 15;
    const int g4 = l >> 4;
    const int b0 = blockIdx.x * 16;

    __shared__ _Float16 zbuf[16][40];
    __shared__ _Float16 buf1[16][72];
    __shared__ _Float16 buf2[16][72];

    f16x8 w1f[4], d1f[4], w2f[4][2], w3f[2][2];
#pragma unroll
    for (int mt = 0; mt < 4; ++mt) {
        const float* p = oW1 + (mt * 16 + c) * 32 + g4 * 8;
        w1f[mt] = pack8(*(const f32x4*)p, *(const f32x4*)(p + 4));
        const float* q = dW1 + (mt * 16 + c) * 32 + g4 * 8;
        d1f[mt] = pack8(*(const f32x4*)q, *(const f32x4*)(q + 4));
#pragma unroll
        for (int kt = 0; kt < 2; ++kt) {
            const float* r = oW2 + (mt * 16 + c) * 64 + kt * 32 + g4 * 8;
            w2f[mt][kt] = pack8(*(const f32x4*)r, *(const f32x4*)(r + 4));
        }
    }
#pragma unroll
    for (int mt = 0; mt < 2; ++mt) {
#pragma unroll
        for (int kt = 0; kt < 2; ++kt) {
            const float* r = oW3 + (mt * 16 + c) * 64 + kt * 32 + g4 * 8;
            w3f[mt][kt] = pack8(*(const f32x4*)r, *(const f32x4*)(r + 4));
        }
    }

    f32x4 b1q[4], b2q[4], d1q[4], w2q[4], b3q[2];
#pragma unroll
    for (int mt = 0; mt < 4; ++mt) {
#pragma unroll
        for (int r = 0; r < 4; ++r) {
            b1q[mt][r] = ob1[mt * 16 + g4 * 4 + r];
            b2q[mt][r] = ob2[mt * 16 + g4 * 4 + r];
            d1q[mt][r] = db1[mt * 16 + g4 * 4 + r];
            w2q[mt][r] = dW2[mt * 16 + g4 * 4 + r];
        }
    }
#pragma unroll
    for (int mt = 0; mt < 2; ++mt) {
#pragma unroll
        for (int r = 0; r < 4; ++r) b3q[mt][r] = ob3[mt * 16 + g4 * 4 + r];
    }
    const float bd2 = db2[0];

    f32x4 z[2];
#pragma unroll
    for (int mt = 0; mt < 2; ++mt)
        z[mt] = *(const f32x4*)(z0ws + (size_t)(b0 + c) * L_ + mt * 16 + g4 * 4);

    auto evalf = [&](const f32x4* zin, f32x4* kout) {
#pragma unroll
        for (int mt = 0; mt < 2; ++mt) {
            f16x4 hv;
#pragma unroll
            for (int r = 0; r < 4; ++r) hv[r] = (_Float16)zin[mt][r];
            *(f16x4*)&zbuf[c][mt * 16 + g4 * 4] = hv;
        }
        f16x8 zf = *(const f16x8*)&zbuf[c][g4 * 8];

        f32x4 h1[4];
#pragma unroll
        for (int mt = 0; mt < 4; ++mt) h1[mt] = MFMA16(w1f[mt], zf, b1q[mt]);
#pragma unroll
        for (int mt = 0; mt < 4; ++mt) {
            f16x4 hv;
#pragma unroll
            for (int r = 0; r < 4; ++r) hv[r] = (_Float16)tanh_(h1[mt][r]);
            *(f16x4*)&buf1[c][mt * 16 + g4 * 4] = hv;
        }
        f16x8 a1 = *(const f16x8*)&buf1[c][g4 * 8];
        f16x8 a2 = *(const f16x8*)&buf1[c][32 + g4 * 8];

        f32x4 h2[4];
#pragma unroll
        for (int mt = 0; mt < 4; ++mt) {
            h2[mt] = MFMA16(w2f[mt][0], a1, b2q[mt]);
            h2[mt] = MFMA16(w2f[mt][1], a2, h2[mt]);
        }
#pragma unroll
        for (int mt = 0; mt < 4; ++mt) {
            f16x4 hv;
#pragma unroll
            for (int r = 0; r < 4; ++r) hv[r] = (_Float16)tanh_(h2[mt][r]);
            *(f16x4*)&buf2[c][mt * 16 + g4 * 4] = hv;
        }
        f16x8 a3 = *(const f16x8*)&buf2[c][g4 * 8];
        f16x8 a4 = *(const f16x8*)&buf2[c][32 + g4 * 8];

#pragma unroll
        for (int mt = 0; mt < 2; ++mt) {
            kout[mt] = MFMA16(w3f[mt][0], a3, b3q[mt]);
            kout[mt] = MFMA16(w3f[mt][1], a4, kout[mt]);
        }
    };

    const float dt = 48.0f / (float)NSTEP;
    for (int s = 0; s < NSTEP; ++s) {
        f32x4 k[2], ks[2], zt[2];
        evalf(z, k);
#pragma unroll
        for (int mt = 0; mt < 2; ++mt) { ks[mt] = k[mt]; zt[mt] = z[mt] + k[mt] * (0.5f * dt); }
        evalf(zt, k);
#pragma unroll
        for (int mt = 0; mt < 2; ++mt) { ks[mt] += k[mt] * 2.0f; zt[mt] = z[mt] + k[mt] * (0.5f * dt); }
        evalf(zt, k);
#pragma unroll
        for (int mt = 0; mt < 2; ++mt) { ks[mt] += k[mt] * 2.0f; zt[mt] = z[mt] + k[mt] * dt; }
        evalf(zt, k);
#pragma unroll
        for (int mt = 0; mt < 2; ++mt) z[mt] += (ks[mt] + k[mt]) * (dt / 6.0f);
    }

#pragma unroll
    for (int mt = 0; mt < 2; ++mt) {
        f16x4 hv;
#pragma unroll
        for (int r = 0; r < 4; ++r) hv[r] = (_Float16)z[mt][r];
        *(f16x4*)&zbuf[c][mt * 16 + g4 * 4] = hv;
    }
    f16x8 zf = *(const f16x8*)&zbuf[c][g4 * 8];
    float p = 0.0f;
#pragma unroll
    for (int mt = 0; mt < 4; ++mt) {
        f32x4 d = MFMA16(d1f[mt], zf, d1q[mt]);
#pragma unroll
        for (int r = 0; r < 4; ++r) p += fmaxf(d[r], 0.0f) * w2q[mt][r];
    }
    p += __shfl_xor(p, 16);
    p += __shfl_xor(p, 32);
    if (l < 16) out[b0 + c] = p + bd2;
}

__global__ __launch_bounds__(128) void kl_fin(const float* __restrict__ parts,
                                              float* __restrict__ out)
{
    __shared__ float sred[2];
    const int tid = threadIdx.x;
    float p = parts[tid];
#pragma unroll
    for (int off = 32; off >= 1; off >>= 1) p += __shfl_down(p, off);
    if ((tid & 63) == 0) sred[tid >> 6] = p;
    __syncthreads();
    if (tid == 0) out[B_] = -0.5f * (sred[0] + sred[1]) / (float)(B_ * L_);
}

extern "C" void kernel_launch(void* const* d_in, const int* in_sizes, int n_in,
                              void* d_out, int out_size, void* d_ws, size_t ws_size,
                              hipStream_t stream) {
    const float* values = (const float*)d_in[1];
    const float* mask   = (const float*)d_in[2];
    const int*   seql   = (const int*)d_in[3];
    const float* eps    = (const float*)d_in[4];
    const float* W_ih   = (const float*)d_in[5];
    const float* W_hh   = (const float*)d_in[6];
    const float* b_ih   = (const float*)d_in[7];
    const float* b_hh   = (const float*)d_in[8];
    const float* W_z0   = (const float*)d_in[9];
    const float* b_z0   = (const float*)d_in[10];
    const float* oW1    = (const float*)d_in[11];
    const float* ob1    = (const float*)d_in[12];
    const float* oW2    = (const float*)d_in[13];
    const float* ob2    = (const float*)d_in[14];
    const float* oW3    = (const float*)d_in[15];
    const float* ob3    = (const float*)d_in[16];
    const float* dW1    = (const float*)d_in[17];
    const float* db1    = (const float*)d_in[18];
    const float* dW2    = (const float*)d_in[19];
    const float* db2    = (const float*)d_in[20];
    float* out = (float*)d_out;

    float* z0ws  = (float*)d_ws;
    float* parts = z0ws + (size_t)B_ * L_;

    hipLaunchKernelGGL(gru_kernel, dim3(B_ / 16), dim3(64), 0, stream,
                       values, mask, seql, eps, W_ih, W_hh, b_ih, b_hh, W_z0, b_z0,
                       z0ws, parts);
    hipLaunchKernelGGL(ode_kernel, dim3(B_ / 16), dim3(64), 0, stream,
                       z0ws, oW1, ob1, oW2, ob2, oW3, ob3, dW1, db1, dW2, db2, out);
    hipLaunchKernelGGL(kl_fin, dim3(1), dim3(128), 0, stream, parts, out);
}

// Round 7
// 276.164 us; speedup vs baseline: 1.6105x; 1.6105x over previous
//
#include <hip/hip_runtime.h>

#define B_ 2048
#define T_ 256
#define NV_ 32
#define H_ 64
#define L_ 32
#define OH_ 64
#define NSTEP 12

typedef _Float16 f16x8 __attribute__((ext_vector_type(8)));
typedef _Float16 f16x4 __attribute__((ext_vector_type(4)));
typedef float f32x4 __attribute__((ext_vector_type(4)));

#define MFMA16(a, b, c) __builtin_amdgcn_mfma_f32_16x16x32_f16((a), (b), (c), 0, 0, 0)
#define LOG2E 1.44269504f

__device__ __forceinline__ float rcp_(float x) { return __builtin_amdgcn_rcpf(x); }
// args pre-scaled: sigm2 expects log2e*x, tanh2 expects 2*log2e*x
__device__ __forceinline__ float sigm2(float x) { return rcp_(1.0f + exp2f(-x)); }
__device__ __forceinline__ float tanh2(float x) { return 2.0f * rcp_(1.0f + exp2f(-x)) - 1.0f; }
__device__ __forceinline__ float sigm(float x) { return rcp_(1.0f + __expf(-x)); }
__device__ __forceinline__ float tanh_(float x) { return 2.0f * rcp_(1.0f + __expf(-2.0f * x)) - 1.0f; }

__device__ __forceinline__ f16x8 pack8(f32x4 a, f32x4 b) {
    f16x8 r;
    r[0] = (_Float16)a[0]; r[1] = (_Float16)a[1]; r[2] = (_Float16)a[2]; r[3] = (_Float16)a[3];
    r[4] = (_Float16)b[0]; r[5] = (_Float16)b[1]; r[6] = (_Float16)b[2]; r[7] = (_Float16)b[3];
    return r;
}
__device__ __forceinline__ f16x8 pack8s(f32x4 a, f32x4 b, float s) {
    f16x8 r;
    r[0] = (_Float16)(s * a[0]); r[1] = (_Float16)(s * a[1]);
    r[2] = (_Float16)(s * a[2]); r[3] = (_Float16)(s * a[3]);
    r[4] = (_Float16)(s * b[0]); r[5] = (_Float16)(s * b[1]);
    r[6] = (_Float16)(s * b[2]); r[7] = (_Float16)(s * b[3]);
    return r;
}

#define RAWBAR() asm volatile("s_waitcnt lgkmcnt(0)\n\ts_barrier" ::: "memory")

// ---------------------------------------------------------------------------
// GRU encoder: 64 blocks x 512 threads = TWO independent 16-batch tiles per
// block (tile q = wave>>2), 2 waves per SIMD. R3's per-tile structure (4-wave
// gate-feature split, swapped orientation, packed u32 h exchange, raw
// lgkm-only barrier). The co-resident wave from the OTHER tile has a full
// independent step of work between barriers -> its issue fills our ds_read /
// MFMA-dep / gate-chain stalls (R4's version failed because producer waves
// had only 1-step slack and idled at the same barrier; here both waves on a
// SIMD have symmetric full-step work). log2e folded into weights: sigmoid/
// tanh lose their input mul on the serial gate chain.
// ---------------------------------------------------------------------------
__global__ __launch_bounds__(512) void gru_kernel(
    const float* __restrict__ values, const float* __restrict__ mask,
    const int* __restrict__ seql, const float* __restrict__ eps,
    const float* __restrict__ W_ih, const float* __restrict__ W_hh,
    const float* __restrict__ b_ih, const float* __restrict__ b_hh,
    const float* __restrict__ W_z0, const float* __restrict__ b_z0,
    float* __restrict__ z0ws, float* __restrict__ parts)
{
    const int tid  = threadIdx.x;
    const int wave = tid >> 6;
    const int q    = wave >> 2;          // tile 0/1 within the block
    const int w    = wave & 3;
    const int l    = tid & 63;
    const int c    = l & 15;
    const int g4   = l >> 4;
    const int b0   = blockIdx.x * 32 + q * 16;

    __shared__ unsigned h_u32[2][2][16][36];   // [tile][buf][batch][feat-pair]
    __shared__ float    zp_lds[2][16][68];
    __shared__ float    red_lds[8];

    for (int i = tid; i < 2 * 2 * 16 * 36; i += 512) (&h_u32[0][0][0][0])[i] = 0u;

    // Weight fragments, log2e-prescaled (r,z x log2e; n x 2*log2e).
    // lane (c,g4) holds W[gate*64 + 16w + c][kt*32 + 8g4 + i]
    f16x8 bih[3][2], bhh[3][2];
#pragma unroll
    for (int gate = 0; gate < 3; ++gate) {
        const float sc = (gate == 2) ? (2.0f * LOG2E) : LOG2E;
#pragma unroll
        for (int kt = 0; kt < 2; ++kt) {
            const float* p1 = W_ih + (gate * 64 + w * 16 + c) * 64 + kt * 32 + g4 * 8;
            bih[gate][kt] = pack8s(*(const f32x4*)p1, *(const f32x4*)(p1 + 4), sc);
            const float* p2 = W_hh + (gate * 64 + w * 16 + c) * 64 + kt * 32 + g4 * 8;
            bhh[gate][kt] = pack8s(*(const f32x4*)p2, *(const f32x4*)(p2 + 4), sc);
        }
    }

    // Per-reg bias vectors (same prescale): reg r <-> gate feature 16w+4g4+r
    f32x4 bRq, bZq, bNXq, bNHq;
#pragma unroll
    for (int r = 0; r < 4; ++r) {
        const int f = w * 16 + g4 * 4 + r;
        bRq[r]  = LOG2E * (b_ih[f]      + b_hh[f]);
        bZq[r]  = LOG2E * (b_ih[64 + f] + b_hh[64 + f]);
        bNXq[r] = 2.0f * LOG2E * b_ih[128 + f];
        bNHq[r] = 2.0f * LOG2E * b_hh[128 + f];
    }

    const int sl_c = seql[b0 + c];
    const int tmax = seql[blockIdx.x * 32];   // sorted desc -> block max (both tiles)
    float hp[4] = {0.f, 0.f, 0.f, 0.f};

    const float* vrow = values + (size_t)(b0 + c) * T_ * NV_ + g4 * 8;
    const float* mrow = mask   + (size_t)(b0 + c) * T_ * NV_ + g4 * 8;

    // depth-2 prefetch: named sets A (even t) / B (odd t)
    f32x4 av0, av1, am0, am1, bv0, bv1, bm0, bm1;
    {
        const float* vp = vrow + (T_ - 1) * NV_;
        const float* mp = mrow + (T_ - 1) * NV_;
        av0 = *(const f32x4*)vp; av1 = *(const f32x4*)(vp + 4);
        am0 = *(const f32x4*)mp; am1 = *(const f32x4*)(mp + 4);
    }
    {
        const int tt = (1 < tmax) ? 1 : 0;
        const float* vp = vrow + (T_ - 1 - tt) * NV_;
        const float* mp = mrow + (T_ - 1 - tt) * NV_;
        bv0 = *(const f32x4*)vp; bv1 = *(const f32x4*)(vp + 4);
        bm0 = *(const f32x4*)mp; bm1 = *(const f32x4*)(mp + 4);
    }

    __syncthreads();   // h zero-init visibility

    int cur = 0;

    auto STEP = [&](f32x4& v0, f32x4& v1, f32x4& m0, f32x4& m1, int tc) {
        f16x8 ha0 = *(const f16x8*)&h_u32[q][cur][c][4 * g4];
        f16x8 ha1 = *(const f16x8*)&h_u32[q][cur][c][16 + 4 * g4];

        f16x8 xa0 = pack8(v0, v1);
        f16x8 xa1 = pack8(m0, m1);

        const int tt = (tc + 2 < tmax) ? (tc + 2) : 0;
        const float* vp = vrow + (T_ - 1 - tt) * NV_;
        const float* mp = mrow + (T_ - 1 - tt) * NV_;
        v0 = *(const f32x4*)vp; v1 = *(const f32x4*)(vp + 4);
        m0 = *(const f32x4*)mp; m1 = *(const f32x4*)(mp + 4);

        // x-MFMAs first (independent of ds_read), then h-MFMAs R -> NH -> Z
        f32x4 accR  = MFMA16(bih[0][0], xa0, bRq);
        f32x4 accNX = MFMA16(bih[2][0], xa0, bNXq);
        f32x4 accZ  = MFMA16(bih[1][0], xa0, bZq);
        accR  = MFMA16(bih[0][1], xa1, accR);
        accNX = MFMA16(bih[2][1], xa1, accNX);
        accZ  = MFMA16(bih[1][1], xa1, accZ);

        f32x4 accNH = MFMA16(bhh[2][0], ha0, bNHq);
        accR  = MFMA16(bhh[0][0], ha0, accR);
        accNH = MFMA16(bhh[2][1], ha1, accNH);
        accR  = MFMA16(bhh[0][1], ha1, accR);
        accZ  = MFMA16(bhh[1][0], ha0, accZ);
        accZ  = MFMA16(bhh[1][1], ha1, accZ);

        const bool act = (tc < sl_c);
#pragma unroll
        for (int r = 0; r < 4; ++r) {
            float rr   = sigm2(accR[r]);
            float zz   = sigm2(accZ[r]);
            float nn   = tanh2(accNX[r] + rr * accNH[r]);
            float hnew = nn + zz * (hp[r] - nn);
            if (act) hp[r] = hnew;
        }

        const int nxt = cur ^ 1;
        f16x4 hq;
#pragma unroll
        for (int r = 0; r < 4; ++r) hq[r] = (_Float16)hp[r];
        *(f16x4*)&h_u32[q][nxt][c][8 * w + 2 * g4] = hq;   // b64 store

        RAWBAR();   // lgkm-only: global prefetch stays outstanding
        cur = nxt;
    };

    int t = 0;
    while (true) {
        STEP(av0, av1, am0, am1, t);
        if (t + 1 >= tmax) break;
        STEP(bv0, bv1, bm0, bm1, t + 1);
        t += 2;
        if (t >= tmax) break;
    }

    // z0p^T = W_z0 * h^T + b_z0 : rows 16w+4g4+r, batch c (per tile)
    f16x8 az0f[2];
#pragma unroll
    for (int kt = 0; kt < 2; ++kt) {
        const float* p = W_z0 + (w * 16 + c) * 64 + kt * 32 + g4 * 8;
        az0f[kt] = pack8(*(const f32x4*)p, *(const f32x4*)(p + 4));
    }
    f16x8 hf0 = *(const f16x8*)&h_u32[q][cur][c][4 * g4];
    f16x8 hf1 = *(const f16x8*)&h_u32[q][cur][c][16 + 4 * g4];
    f32x4 az;
#pragma unroll
    for (int r = 0; r < 4; ++r) az[r] = b_z0[w * 16 + g4 * 4 + r];
    az = MFMA16(az0f[0], hf0, az);
    az = MFMA16(az0f[1], hf1, az);
    *(f32x4*)&zp_lds[q][c][w * 16 + g4 * 4] = az;
    __syncthreads();

    // z0 = mean + eps*exp(0.5*logvar); KL partial (512 thr = 2 tiles x 16 x 16)
    {
        const int qt  = tid >> 8;
        const int row = (tid >> 4) & 15;
        const int j2  = (tid & 15) * 2;
        const int bg  = blockIdx.x * 32 + qt * 16 + row;
        float m0 = zp_lds[qt][row][j2],      m1 = zp_lds[qt][row][j2 + 1];
        float v0 = zp_lds[qt][row][32 + j2], v1 = zp_lds[qt][row][32 + j2 + 1];
        const float* erow = eps + (size_t)bg * L_;
        float e0 = erow[j2], e1 = erow[j2 + 1];
        float* zrow = z0ws + (size_t)bg * L_;
        float s0 = __expf(0.5f * v0), s1 = __expf(0.5f * v1);
        zrow[j2]     = m0 + e0 * s0;
        zrow[j2 + 1] = m1 + e1 * s1;
        float kls = (1.0f + v0 - m0 * m0 - s0 * s0) + (1.0f + v1 - m1 * m1 - s1 * s1);
#pragma unroll
        for (int off = 32; off >= 1; off >>= 1) kls += __shfl_down(kls, off);
        if (l == 0) red_lds[wave] = kls;
    }
    __syncthreads();
    if (tid == 0) {
        float s = 0.0f;
#pragma unroll
        for (int i = 0; i < 8; ++i) s += red_lds[i];
        parts[blockIdx.x] = s;
    }
}

// ---------------------------------------------------------------------------
// ODE (RK4, NSTEP steps over [0,48]) + decoder; block 0 also finishes the KL.
// ---------------------------------------------------------------------------
__global__ __launch_bounds__(64) void ode_kernel(
    const float* __restrict__ z0ws, const float* __restrict__ parts,
    const float* __restrict__ oW1, const float* __restrict__ ob1,
    const float* __restrict__ oW2, const float* __restrict__ ob2,
    const float* __restrict__ oW3, const float* __restrict__ ob3,
    const float* __restrict__ dW1, const float* __restrict__ db1,
    const float* __restrict__ dW2, const float* __restrict__ db2,
    float* __restrict__ out)
{
    const int l  = threadIdx.x;
    const int c  = l & 15;
    const int g4 = l >> 4;
    const int b0 = blockIdx.x * 16;

    __shared__ _Float16 zbuf[16][40];
    __shared__ _Float16 buf1[16][72];
    __shared__ _Float16 buf2[16][72];

    f16x8 w1f[4], d1f[4], w2f[4][2], w3f[2][2];
#pragma unroll
    for (int mt = 0; mt < 4; ++mt) {
        const float* p = oW1 + (mt * 16 + c) * 32 + g4 * 8;
        w1f[mt] = pack8(*(const f32x4*)p, *(const f32x4*)(p + 4));
        const float* qq = dW1 + (mt * 16 + c) * 32 + g4 * 8;
        d1f[mt] = pack8(*(const f32x4*)qq, *(const f32x4*)(qq + 4));
#pragma unroll
        for (int kt = 0; kt < 2; ++kt) {
            const float* r = oW2 + (mt * 16 + c) * 64 + kt * 32 + g4 * 8;
            w2f[mt][kt] = pack8(*(const f32x4*)r, *(const f32x4*)(r + 4));
        }
    }
#pragma unroll
    for (int mt = 0; mt < 2; ++mt) {
#pragma unroll
        for (int kt = 0; kt < 2; ++kt) {
            const float* r = oW3 + (mt * 16 + c) * 64 + kt * 32 + g4 * 8;
            w3f[mt][kt] = pack8(*(const f32x4*)r, *(const f32x4*)(r + 4));
        }
    }

    f32x4 b1q[4], b2q[4], d1q[4], w2q[4], b3q[2];
#pragma unroll
    for (int mt = 0; mt < 4; ++mt) {
#pragma unroll
        for (int r = 0; r < 4; ++r) {
            b1q[mt][r] = ob1[mt * 16 + g4 * 4 + r];
            b2q[mt][r] = ob2[mt * 16 + g4 * 4 + r];
            d1q[mt][r] = db1[mt * 16 + g4 * 4 + r];
            w2q[mt][r] = dW2[mt * 16 + g4 * 4 + r];
        }
    }
#pragma unroll
    for (int mt = 0; mt < 2; ++mt) {
#pragma unroll
        for (int r = 0; r < 4; ++r) b3q[mt][r] = ob3[mt * 16 + g4 * 4 + r];
    }
    const float bd2 = db2[0];

    f32x4 z[2];
#pragma unroll
    for (int mt = 0; mt < 2; ++mt)
        z[mt] = *(const f32x4*)(z0ws + (size_t)(b0 + c) * L_ + mt * 16 + g4 * 4);

    auto evalf = [&](const f32x4* zin, f32x4* kout) {
#pragma unroll
        for (int mt = 0; mt < 2; ++mt) {
            f16x4 hv;
#pragma unroll
            for (int r = 0; r < 4; ++r) hv[r] = (_Float16)zin[mt][r];
            *(f16x4*)&zbuf[c][mt * 16 + g4 * 4] = hv;
        }
        f16x8 zf = *(const f16x8*)&zbuf[c][g4 * 8];

        f32x4 h1[4];
#pragma unroll
        for (int mt = 0; mt < 4; ++mt) h1[mt] = MFMA16(w1f[mt], zf, b1q[mt]);
#pragma unroll
        for (int mt = 0; mt < 4; ++mt) {
            f16x4 hv;
#pragma unroll
            for (int r = 0; r < 4; ++r) hv[r] = (_Float16)tanh_(h1[mt][r]);
            *(f16x4*)&buf1[c][mt * 16 + g4 * 4] = hv;
        }
        f16x8 a1 = *(const f16x8*)&buf1[c][g4 * 8];
        f16x8 a2 = *(const f16x8*)&buf1[c][32 + g4 * 8];

        f32x4 h2[4];
#pragma unroll
        for (int mt = 0; mt < 4; ++mt) {
            h2[mt] = MFMA16(w2f[mt][0], a1, b2q[mt]);
            h2[mt] = MFMA16(w2f[mt][1], a2, h2[mt]);
        }
#pragma unroll
        for (int mt = 0; mt < 4; ++mt) {
            f16x4 hv;
#pragma unroll
            for (int r = 0; r < 4; ++r) hv[r] = (_Float16)tanh_(h2[mt][r]);
            *(f16x4*)&buf2[c][mt * 16 + g4 * 4] = hv;
        }
        f16x8 a3 = *(const f16x8*)&buf2[c][g4 * 8];
        f16x8 a4 = *(const f16x8*)&buf2[c][32 + g4 * 8];

#pragma unroll
        for (int mt = 0; mt < 2; ++mt) {
            kout[mt] = MFMA16(w3f[mt][0], a3, b3q[mt]);
            kout[mt] = MFMA16(w3f[mt][1], a4, kout[mt]);
        }
    };

    const float dt = 48.0f / (float)NSTEP;
    for (int s = 0; s < NSTEP; ++s) {
        f32x4 k[2], ks[2], zt[2];
        evalf(z, k);
#pragma unroll
        for (int mt = 0; mt < 2; ++mt) { ks[mt] = k[mt]; zt[mt] = z[mt] + k[mt] * (0.5f * dt); }
        evalf(zt, k);
#pragma unroll
        for (int mt = 0; mt < 2; ++mt) { ks[mt] += k[mt] * 2.0f; zt[mt] = z[mt] + k[mt] * (0.5f * dt); }
        evalf(zt, k);
#pragma unroll
        for (int mt = 0; mt < 2; ++mt) { ks[mt] += k[mt] * 2.0f; zt[mt] = z[mt] + k[mt] * dt; }
        evalf(zt, k);
#pragma unroll
        for (int mt = 0; mt < 2; ++mt) z[mt] += (ks[mt] + k[mt]) * (dt / 6.0f);
    }

#pragma unroll
    for (int mt = 0; mt < 2; ++mt) {
        f16x4 hv;
#pragma unroll
        for (int r = 0; r < 4; ++r) hv[r] = (_Float16)z[mt][r];
        *(f16x4*)&zbuf[c][mt * 16 + g4 * 4] = hv;
    }
    f16x8 zf = *(const f16x8*)&zbuf[c][g4 * 8];
    float p = 0.0f;
#pragma unroll
    for (int mt = 0; mt < 4; ++mt) {
        f32x4 d = MFMA16(d1f[mt], zf, d1q[mt]);
#pragma unroll
        for (int r = 0; r < 4; ++r) p += fmaxf(d[r], 0.0f) * w2q[mt][r];
    }
    p += __shfl_xor(p, 16);
    p += __shfl_xor(p, 32);
    if (l < 16) out[b0 + c] = p + bd2;

    // KL finish (block 0): parts has 64 entries (one per gru block)
    if (blockIdx.x == 0) {
        float kp = parts[l & 63];
#pragma unroll
        for (int off = 32; off >= 1; off >>= 1) kp += __shfl_down(kp, off);
        if (l == 0) out[B_] = -0.5f * kp / (float)(B_ * L_);
    }
}

extern "C" void kernel_launch(void* const* d_in, const int* in_sizes, int n_in,
                              void* d_out, int out_size, void* d_ws, size_t ws_size,
                              hipStream_t stream) {
    const float* values = (const float*)d_in[1];
    const float* mask   = (const float*)d_in[2];
    const int*   seql   = (const int*)d_in[3];
    const float* eps    = (const float*)d_in[4];
    const float* W_ih   = (const float*)d_in[5];
    const float* W_hh   = (const float*)d_in[6];
    const float* b_ih   = (const float*)d_in[7];
    const float* b_hh   = (const float*)d_in[8];
    const float* W_z0   = (const float*)d_in[9];
    const float* b_z0   = (const float*)d_in[10];
    const float* oW1    = (const float*)d_in[11];
    const float* ob1    = (const float*)d_in[12];
    const float* oW2    = (const float*)d_in[13];
    const float* ob2    = (const float*)d_in[14];
    const float* oW3    = (const float*)d_in[15];
    const float* ob3    = (const float*)d_in[16];
    const float* dW1    = (const float*)d_in[17];
    const float* db1    = (const float*)d_in[18];
    const float* dW2    = (const float*)d_in[19];
    const float* db2    = (const float*)d_in[20];
    float* out = (float*)d_out;

    float* z0ws  = (float*)d_ws;
    float* parts = z0ws + (size_t)B_ * L_;

    hipLaunchKernelGGL(gru_kernel, dim3(B_ / 32), dim3(512), 0, stream,
                       values, mask, seql, eps, W_ih, W_hh, b_ih, b_hh, W_z0, b_z0,
                       z0ws, parts);
    hipLaunchKernelGGL(ode_kernel, dim3(B_ / 16), dim3(64), 0, stream,
                       z0ws, parts, oW1, ob1, oW2, ob2, oW3, ob3, dW1, db1, dW2, db2, out);
}

// Round 9
// 215.066 us; speedup vs baseline: 2.0680x; 1.2841x over previous
//
#include <hip/hip_runtime.h>

#define B_ 2048
#define T_ 256
#define NV_ 32
#define H_ 64
#define L_ 32
#define OH_ 64
#define NSTEP 12

typedef _Float16 f16x8 __attribute__((ext_vector_type(8)));
typedef _Float16 f16x4 __attribute__((ext_vector_type(4)));
typedef float f32x4 __attribute__((ext_vector_type(4)));

#define MFMA16(a, b, c) __builtin_amdgcn_mfma_f32_16x16x32_f16((a), (b), (c), 0, 0, 0)
#define LOG2E 1.44269504f

__device__ __forceinline__ float rcp_(float x) { return __builtin_amdgcn_rcpf(x); }
// args pre-scaled: sigm2 expects log2e*x, tanh2 expects 2*log2e*x
__device__ __forceinline__ float sigm2(float x) { return rcp_(1.0f + exp2f(-x)); }
__device__ __forceinline__ float tanh2(float x) { return 2.0f * rcp_(1.0f + exp2f(-x)) - 1.0f; }
__device__ __forceinline__ float sigm(float x) { return rcp_(1.0f + __expf(-x)); }
__device__ __forceinline__ float tanh_(float x) { return 2.0f * rcp_(1.0f + __expf(-2.0f * x)) - 1.0f; }

__device__ __forceinline__ f16x8 pack8(f32x4 a, f32x4 b) {
    f16x8 r;
    r[0] = (_Float16)a[0]; r[1] = (_Float16)a[1]; r[2] = (_Float16)a[2]; r[3] = (_Float16)a[3];
    r[4] = (_Float16)b[0]; r[5] = (_Float16)b[1]; r[6] = (_Float16)b[2]; r[7] = (_Float16)b[3];
    return r;
}
__device__ __forceinline__ f16x8 pack8s(f32x4 a, f32x4 b, float s) {
    f16x8 r;
    r[0] = (_Float16)(s * a[0]); r[1] = (_Float16)(s * a[1]);
    r[2] = (_Float16)(s * a[2]); r[3] = (_Float16)(s * a[3]);
    r[4] = (_Float16)(s * b[0]); r[5] = (_Float16)(s * b[1]);
    r[6] = (_Float16)(s * b[2]); r[7] = (_Float16)(s * b[3]);
    return r;
}
__device__ __forceinline__ unsigned pk_u32(float a, float b) {
    return __builtin_bit_cast(unsigned, __builtin_amdgcn_cvt_pkrtz(a, b));
}

// ---------------------------------------------------------------------------
// GRU encoder: 128 blocks x 4 waves (R3 structure: swapped orientation,
// wave w owns gate features 16w..16w+15, packed-u32 h exchange, raw
// lgkm-only barrier). This round compresses the per-step critical chain:
//  - K-split h-MFMAs: k0 and k1 halves independent (C=0 for k1) + VALU add;
//    k0-MFMAs start as soon as ha0 lands (pipelines the two ds_reads).
//  - x-projection xp[t+1] (x-MFMAs + biases) hoisted into step t's gate
//    stall window: post-barrier chain starts directly with h-MFMAs whose
//    C-init is the precomputed xp.
//  - Two unrolled bodies with compile-time LDS buffer addresses; cvt_pkrtz
//    packing; R->tanh gate ordering with Z in the tanh shadow.
// ---------------------------------------------------------------------------
__global__ __launch_bounds__(256) void gru_kernel(
    const float* __restrict__ values, const float* __restrict__ mask,
    const int* __restrict__ seql, const float* __restrict__ eps,
    const float* __restrict__ W_ih, const float* __restrict__ W_hh,
    const float* __restrict__ b_ih, const float* __restrict__ b_hh,
    const float* __restrict__ W_z0, const float* __restrict__ b_z0,
    float* __restrict__ z0ws, float* __restrict__ parts)
{
    const int tid = threadIdx.x;
    const int w   = tid >> 6;
    const int l   = tid & 63;
    const int c   = l & 15;
    const int g4  = l >> 4;
    const int b0  = blockIdx.x * 16;

    __shared__ unsigned h_u32[2][16][36];   // packed f16 pairs [buf][batch][feat-pair]
    __shared__ float    zp_lds[16][68];
    __shared__ float    red_lds[4];

    for (int i = tid; i < 2 * 16 * 36; i += 256) (&h_u32[0][0][0])[i] = 0u;

    // Weight fragments, log2e-prescaled (r,z x log2e; n x 2*log2e).
    f16x8 bihR[2], bihZ[2], bihN[2], bhhR[2], bhhZ[2], bhhN[2];
#pragma unroll
    for (int kt = 0; kt < 2; ++kt) {
        const float* p;
        p = W_ih + (0 * 64 + w * 16 + c) * 64 + kt * 32 + g4 * 8;
        bihR[kt] = pack8s(*(const f32x4*)p, *(const f32x4*)(p + 4), LOG2E);
        p = W_ih + (1 * 64 + w * 16 + c) * 64 + kt * 32 + g4 * 8;
        bihZ[kt] = pack8s(*(const f32x4*)p, *(const f32x4*)(p + 4), LOG2E);
        p = W_ih + (2 * 64 + w * 16 + c) * 64 + kt * 32 + g4 * 8;
        bihN[kt] = pack8s(*(const f32x4*)p, *(const f32x4*)(p + 4), 2.0f * LOG2E);
        p = W_hh + (0 * 64 + w * 16 + c) * 64 + kt * 32 + g4 * 8;
        bhhR[kt] = pack8s(*(const f32x4*)p, *(const f32x4*)(p + 4), LOG2E);
        p = W_hh + (1 * 64 + w * 16 + c) * 64 + kt * 32 + g4 * 8;
        bhhZ[kt] = pack8s(*(const f32x4*)p, *(const f32x4*)(p + 4), LOG2E);
        p = W_hh + (2 * 64 + w * 16 + c) * 64 + kt * 32 + g4 * 8;
        bhhN[kt] = pack8s(*(const f32x4*)p, *(const f32x4*)(p + 4), 2.0f * LOG2E);
    }

    f32x4 bRq, bZq, bNXq, bNHq;
#pragma unroll
    for (int r = 0; r < 4; ++r) {
        const int f = w * 16 + g4 * 4 + r;
        bRq[r]  = LOG2E * (b_ih[f]      + b_hh[f]);
        bZq[r]  = LOG2E * (b_ih[64 + f] + b_hh[64 + f]);
        bNXq[r] = 2.0f * LOG2E * b_ih[128 + f];
        bNHq[r] = 2.0f * LOG2E * b_hh[128 + f];
    }
    const f32x4 Z4 = {0.f, 0.f, 0.f, 0.f};

    const int sl_c = seql[b0 + c];
    const int tmax = seql[b0];       // sorted descending -> block max
    float hp[4] = {0.f, 0.f, 0.f, 0.f};

    const float* vrow = values + (size_t)(b0 + c) * T_ * NV_ + g4 * 8;
    const float* mrow = mask   + (size_t)(b0 + c) * T_ * NV_ + g4 * 8;

    // depth-2 prefetch: set A = even t, set B = odd t
    f32x4 av0, av1, am0, am1, bv0, bv1, bm0, bm1;
#define FILLSET(S, tc) do {                                                  \
        const int tt_ = ((tc) < tmax) ? (tc) : 0;                            \
        const float* vp_ = vrow + (T_ - 1 - tt_) * NV_;                      \
        const float* mp_ = mrow + (T_ - 1 - tt_) * NV_;                      \
        S##v0 = *(const f32x4*)vp_; S##v1 = *(const f32x4*)(vp_ + 4);        \
        S##m0 = *(const f32x4*)mp_; S##m1 = *(const f32x4*)(mp_ + 4);        \
    } while (0)
    FILLSET(a, 0); FILLSET(b, 1);

    // prologue: xp for t = 0 from set A; refill A for t = 2
    f32x4 xpR, xpZ, xpNX;
    {
        f16x8 xa0 = pack8(av0, av1);
        f16x8 xa1 = pack8(am0, am1);
        FILLSET(a, 2);
        xpR  = MFMA16(bihR[0], xa0, bRq);  xpR  = MFMA16(bihR[1], xa1, xpR);
        xpZ  = MFMA16(bihZ[0], xa0, bZq);  xpZ  = MFMA16(bihZ[1], xa1, xpZ);
        xpNX = MFMA16(bihN[0], xa0, bNXq); xpNX = MFMA16(bihN[1], xa1, xpNX);
    }

    __syncthreads();   // h zero-init visibility

    // STEPB: consume xp[tc] and h[tc] (buf RB) -> h[tc+1] (buf WB);
    // then compute xp[tc+1] from prefetch set SN (holding x[tc+1]) and
    // refill SN for tc+3. The xp/FILLSET work interleaves into the gate
    // chain's stall slots (independent of h). lgkm drain covers only the
    // two h-writes; global prefetch stays in flight across the barrier.
#define STEPB(SN, tc, RB, WB) do {                                           \
        f16x8 ha0 = *(const f16x8*)&h_u32[RB][c][4 * g4];                    \
        f16x8 ha1 = *(const f16x8*)&h_u32[RB][c][16 + 4 * g4];               \
        /* k0-half (needs ha0 only), C-init = ready xp */                     \
        f32x4 aR  = MFMA16(bhhR[0], ha0, xpR);                               \
        f32x4 aNH = MFMA16(bhhN[0], ha0, bNHq);                              \
        f32x4 aZ  = MFMA16(bhhZ[0], ha0, xpZ);                               \
        /* k1-half (needs ha1), K-split with zero C */                        \
        f32x4 aR1  = MFMA16(bhhR[1], ha1, Z4);                               \
        f32x4 aNH1 = MFMA16(bhhN[1], ha1, Z4);                               \
        f32x4 aZ1  = MFMA16(bhhZ[1], ha1, Z4);                               \
        /* xp[tc+1]: independent work the scheduler packs into stalls */      \
        f16x8 xa0 = pack8(SN##v0, SN##v1);                                   \
        f16x8 xa1 = pack8(SN##m0, SN##m1);                                   \
        FILLSET(SN, (tc) + 3);                                               \
        f32x4 nxpR  = MFMA16(bihR[0], xa0, bRq);                             \
        f32x4 nxpZ  = MFMA16(bihZ[0], xa0, bZq);                             \
        f32x4 nxpNX = MFMA16(bihN[0], xa0, bNXq);                            \
        nxpR  = MFMA16(bihR[1], xa1, nxpR);                                  \
        nxpZ  = MFMA16(bihZ[1], xa1, nxpZ);                                  \
        nxpNX = MFMA16(bihN[1], xa1, nxpNX);                                 \
        aR  += aR1;  aNH += aNH1;  aZ += aZ1;                                \
        const bool act = ((tc) < sl_c);                                      \
        _Pragma("unroll")                                                    \
        for (int r = 0; r < 4; ++r) {                                        \
            float rr   = sigm2(aR[r]);                                       \
            float nn   = tanh2(xpNX[r] + rr * aNH[r]);                       \
            float zz   = sigm2(aZ[r]);                                       \
            float hnew = nn + zz * (hp[r] - nn);                             \
            if (act) hp[r] = hnew;                                           \
        }                                                                    \
        h_u32[WB][c][8 * w + 2 * g4]     = pk_u32(hp[0], hp[1]);             \
        h_u32[WB][c][8 * w + 2 * g4 + 1] = pk_u32(hp[2], hp[3]);             \
        xpR = nxpR; xpZ = nxpZ; xpNX = nxpNX;                                \
        asm volatile("s_waitcnt lgkmcnt(0)\n\ts_barrier" ::: "memory");      \
    } while (0)

    int t = 0;
    while (true) {
        STEPB(b, t, 0, 1);          // even t: read buf0, write buf1; next x from B
        if (++t >= tmax) break;
        STEPB(a, t, 1, 0);          // odd t: read buf1, write buf0; next x from A
        if (++t >= tmax) break;
    }

    // z0p^T = W_z0 * h^T + b_z0 : rows 16w+4g4+r, batch c
    f16x8 az0f[2];
#pragma unroll
    for (int kt = 0; kt < 2; ++kt) {
        const float* p = W_z0 + (w * 16 + c) * 64 + kt * 32 + g4 * 8;
        az0f[kt] = pack8(*(const f32x4*)p, *(const f32x4*)(p + 4));
    }
    const int fin = tmax & 1;
    f16x8 hf0 = *(const f16x8*)&h_u32[fin][c][4 * g4];
    f16x8 hf1 = *(const f16x8*)&h_u32[fin][c][16 + 4 * g4];
    f32x4 az;
#pragma unroll
    for (int r = 0; r < 4; ++r) az[r] = b_z0[w * 16 + g4 * 4 + r];
    az = MFMA16(az0f[0], hf0, az);
    az = MFMA16(az0f[1], hf1, az);
    *(f32x4*)&zp_lds[c][w * 16 + g4 * 4] = az;
    __syncthreads();

    // z0 = mean + eps*exp(0.5*logvar); KL partial sum
    const int row = tid >> 4;
    const int j2  = (tid & 15) * 2;
    float m0 = zp_lds[row][j2],      m1 = zp_lds[row][j2 + 1];
    float v0 = zp_lds[row][32 + j2], v1 = zp_lds[row][32 + j2 + 1];
    const float* erow = eps + (size_t)(b0 + row) * L_;
    float e0 = erow[j2], e1 = erow[j2 + 1];
    float* zrow = z0ws + (size_t)(b0 + row) * L_;
    float s0 = __expf(0.5f * v0), s1 = __expf(0.5f * v1);
    zrow[j2]     = m0 + e0 * s0;
    zrow[j2 + 1] = m1 + e1 * s1;
    float kls = (1.0f + v0 - m0 * m0 - s0 * s0) + (1.0f + v1 - m1 * m1 - s1 * s1);
#pragma unroll
    for (int off = 32; off >= 1; off >>= 1) kls += __shfl_down(kls, off);
    if (l == 0) red_lds[w] = kls;
    __syncthreads();
    if (tid == 0) parts[blockIdx.x] = red_lds[0] + red_lds[1] + red_lds[2] + red_lds[3];
}

// ---------------------------------------------------------------------------
// ODE (RK4, NSTEP steps over [0,48]) + decoder; block 0 also finishes the KL.
// ---------------------------------------------------------------------------
__global__ __launch_bounds__(64) void ode_kernel(
    const float* __restrict__ z0ws, const float* __restrict__ parts,
    const float* __restrict__ oW1, const float* __restrict__ ob1,
    const float* __restrict__ oW2, const float* __restrict__ ob2,
    const float* __restrict__ oW3, const float* __restrict__ ob3,
    const float* __restrict__ dW1, const float* __restrict__ db1,
    const float* __restrict__ dW2, const float* __restrict__ db2,
    float* __restrict__ out)
{
    const int l  = threadIdx.x;
    const int c  = l & 15;
    const int g4 = l >> 4;
    const int b0 = blockIdx.x * 16;

    __shared__ _Float16 zbuf[16][40];
    __shared__ _Float16 buf1[16][72];
    __shared__ _Float16 buf2[16][72];

    f16x8 w1f[4], d1f[4], w2f[4][2], w3f[2][2];
#pragma unroll
    for (int mt = 0; mt < 4; ++mt) {
        const float* p = oW1 + (mt * 16 + c) * 32 + g4 * 8;
        w1f[mt] = pack8(*(const f32x4*)p, *(const f32x4*)(p + 4));
        const float* qq = dW1 + (mt * 16 + c) * 32 + g4 * 8;
        d1f[mt] = pack8(*(const f32x4*)qq, *(const f32x4*)(qq + 4));
#pragma unroll
        for (int kt = 0; kt < 2; ++kt) {
            const float* r = oW2 + (mt * 16 + c) * 64 + kt * 32 + g4 * 8;
            w2f[mt][kt] = pack8(*(const f32x4*)r, *(const f32x4*)(r + 4));
        }
    }
#pragma unroll
    for (int mt = 0; mt < 2; ++mt) {
#pragma unroll
        for (int kt = 0; kt < 2; ++kt) {
            const float* r = oW3 + (mt * 16 + c) * 64 + kt * 32 + g4 * 8;
            w3f[mt][kt] = pack8(*(const f32x4*)r, *(const f32x4*)(r + 4));
        }
    }

    f32x4 b1q[4], b2q[4], d1q[4], w2q[4], b3q[2];
#pragma unroll
    for (int mt = 0; mt < 4; ++mt) {
#pragma unroll
        for (int r = 0; r < 4; ++r) {
            b1q[mt][r] = ob1[mt * 16 + g4 * 4 + r];
            b2q[mt][r] = ob2[mt * 16 + g4 * 4 + r];
            d1q[mt][r] = db1[mt * 16 + g4 * 4 + r];
            w2q[mt][r] = dW2[mt * 16 + g4 * 4 + r];
        }
    }
#pragma unroll
    for (int mt = 0; mt < 2; ++mt) {
#pragma unroll
        for (int r = 0; r < 4; ++r) b3q[mt][r] = ob3[mt * 16 + g4 * 4 + r];
    }
    const float bd2 = db2[0];

    f32x4 z[2];
#pragma unroll
    for (int mt = 0; mt < 2; ++mt)
        z[mt] = *(const f32x4*)(z0ws + (size_t)(b0 + c) * L_ + mt * 16 + g4 * 4);

    auto evalf = [&](const f32x4* zin, f32x4* kout) {
#pragma unroll
        for (int mt = 0; mt < 2; ++mt) {
            f16x4 hv;
#pragma unroll
            for (int r = 0; r < 4; ++r) hv[r] = (_Float16)zin[mt][r];
            *(f16x4*)&zbuf[c][mt * 16 + g4 * 4] = hv;
        }
        f16x8 zf = *(const f16x8*)&zbuf[c][g4 * 8];

        f32x4 h1[4];
#pragma unroll
        for (int mt = 0; mt < 4; ++mt) h1[mt] = MFMA16(w1f[mt], zf, b1q[mt]);
#pragma unroll
        for (int mt = 0; mt < 4; ++mt) {
            f16x4 hv;
#pragma unroll
            for (int r = 0; r < 4; ++r) hv[r] = (_Float16)tanh_(h1[mt][r]);
            *(f16x4*)&buf1[c][mt * 16 + g4 * 4] = hv;
        }
        f16x8 a1 = *(const f16x8*)&buf1[c][g4 * 8];
        f16x8 a2 = *(const f16x8*)&buf1[c][32 + g4 * 8];

        f32x4 h2[4];
#pragma unroll
        for (int mt = 0; mt < 4; ++mt) {
            h2[mt] = MFMA16(w2f[mt][0], a1, b2q[mt]);
            h2[mt] = MFMA16(w2f[mt][1], a2, h2[mt]);
        }
#pragma unroll
        for (int mt = 0; mt < 4; ++mt) {
            f16x4 hv;
#pragma unroll
            for (int r = 0; r < 4; ++r) hv[r] = (_Float16)tanh_(h2[mt][r]);
            *(f16x4*)&buf2[c][mt * 16 + g4 * 4] = hv;
        }
        f16x8 a3 = *(const f16x8*)&buf2[c][g4 * 8];
        f16x8 a4 = *(const f16x8*)&buf2[c][32 + g4 * 8];

#pragma unroll
        for (int mt = 0; mt < 2; ++mt) {
            kout[mt] = MFMA16(w3f[mt][0], a3, b3q[mt]);
            kout[mt] = MFMA16(w3f[mt][1], a4, kout[mt]);
        }
    };

    const float dt = 48.0f / (float)NSTEP;
    for (int s = 0; s < NSTEP; ++s) {
        f32x4 k[2], ks[2], zt[2];
        evalf(z, k);
#pragma unroll
        for (int mt = 0; mt < 2; ++mt) { ks[mt] = k[mt]; zt[mt] = z[mt] + k[mt] * (0.5f * dt); }
        evalf(zt, k);
#pragma unroll
        for (int mt = 0; mt < 2; ++mt) { ks[mt] += k[mt] * 2.0f; zt[mt] = z[mt] + k[mt] * (0.5f * dt); }
        evalf(zt, k);
#pragma unroll
        for (int mt = 0; mt < 2; ++mt) { ks[mt] += k[mt] * 2.0f; zt[mt] = z[mt] + k[mt] * dt; }
        evalf(zt, k);
#pragma unroll
        for (int mt = 0; mt < 2; ++mt) z[mt] += (ks[mt] + k[mt]) * (dt / 6.0f);
    }

#pragma unroll
    for (int mt = 0; mt < 2; ++mt) {
        f16x4 hv;
#pragma unroll
        for (int r = 0; r < 4; ++r) hv[r] = (_Float16)z[mt][r];
        *(f16x4*)&zbuf[c][mt * 16 + g4 * 4] = hv;
    }
    f16x8 zf = *(const f16x8*)&zbuf[c][g4 * 8];
    float p = 0.0f;
#pragma unroll
    for (int mt = 0; mt < 4; ++mt) {
        f32x4 d = MFMA16(d1f[mt], zf, d1q[mt]);
#pragma unroll
        for (int r = 0; r < 4; ++r) p += fmaxf(d[r], 0.0f) * w2q[mt][r];
    }
    p += __shfl_xor(p, 16);
    p += __shfl_xor(p, 32);
    if (l < 16) out[b0 + c] = p + bd2;

    // KL finish (block 0): parts has 128 entries (one per gru block)
    if (blockIdx.x == 0) {
        float kp = parts[l] + parts[l + 64];
#pragma unroll
        for (int off = 32; off >= 1; off >>= 1) kp += __shfl_down(kp, off);
        if (l == 0) out[B_] = -0.5f * kp / (float)(B_ * L_);
    }
}

extern "C" void kernel_launch(void* const* d_in, const int* in_sizes, int n_in,
                              void* d_out, int out_size, void* d_ws, size_t ws_size,
                              hipStream_t stream) {
    const float* values = (const float*)d_in[1];
    const float* mask   = (const float*)d_in[2];
    const int*   seql   = (const int*)d_in[3];
    const float* eps    = (const float*)d_in[4];
    const float* W_ih   = (const float*)d_in[5];
    const float* W_hh   = (const float*)d_in[6];
    const float* b_ih   = (const float*)d_in[7];
    const float* b_hh   = (const float*)d_in[8];
    const float* W_z0   = (const float*)d_in[9];
    const float* b_z0   = (const float*)d_in[10];
    const float* oW1    = (const float*)d_in[11];
    const float* ob1    = (const float*)d_in[12];
    const float* oW2    = (const float*)d_in[13];
    const float* ob2    = (const float*)d_in[14];
    const float* oW3    = (const float*)d_in[15];
    const float* ob3    = (const float*)d_in[16];
    const float* dW1    = (const float*)d_in[17];
    const float* db1    = (const float*)d_in[18];
    const float* dW2    = (const float*)d_in[19];
    const float* db2    = (const float*)d_in[20];
    float* out = (float*)d_out;

    float* z0ws  = (float*)d_ws;
    float* parts = z0ws + (size_t)B_ * L_;

    hipLaunchKernelGGL(gru_kernel, dim3(B_ / 16), dim3(256), 0, stream,
                       values, mask, seql, eps, W_ih, W_hh, b_ih, b_hh, W_z0, b_z0,
                       z0ws, parts);
    hipLaunchKernelGGL(ode_kernel, dim3(B_ / 16), dim3(64), 0, stream,
                       z0ws, parts, oW1, ob1, oW2, ob2, oW3, ob3, dW1, db1, dW2, db2, out);
}

// Round 10
// 195.668 us; speedup vs baseline: 2.2730x; 1.0991x over previous
//
#include <hip/hip_runtime.h>

#define B_ 2048
#define T_ 256
#define NV_ 32
#define H_ 64
#define L_ 32
#define OH_ 64
#define NSTEP 12

typedef _Float16 f16x8 __attribute__((ext_vector_type(8)));
typedef _Float16 f16x4 __attribute__((ext_vector_type(4)));
typedef float f32x4 __attribute__((ext_vector_type(4)));

#define MFMA16(a, b, c) __builtin_amdgcn_mfma_f32_16x16x32_f16((a), (b), (c), 0, 0, 0)
#define LOG2E 1.44269504f

__device__ __forceinline__ float rcp_(float x) { return __builtin_amdgcn_rcpf(x); }
// args pre-scaled: sigm2 expects log2e*x, tanh2 expects 2*log2e*x
__device__ __forceinline__ float sigm2(float x) { return rcp_(1.0f + exp2f(-x)); }
__device__ __forceinline__ float tanh2(float x) { return 2.0f * rcp_(1.0f + exp2f(-x)) - 1.0f; }
__device__ __forceinline__ float sigm(float x) { return rcp_(1.0f + __expf(-x)); }
__device__ __forceinline__ float tanh_(float x) { return 2.0f * rcp_(1.0f + __expf(-2.0f * x)) - 1.0f; }

__device__ __forceinline__ f16x8 pack8(f32x4 a, f32x4 b) {
    f16x8 r;
    r[0] = (_Float16)a[0]; r[1] = (_Float16)a[1]; r[2] = (_Float16)a[2]; r[3] = (_Float16)a[3];
    r[4] = (_Float16)b[0]; r[5] = (_Float16)b[1]; r[6] = (_Float16)b[2]; r[7] = (_Float16)b[3];
    return r;
}
__device__ __forceinline__ f16x8 pack8s(f32x4 a, f32x4 b, float s) {
    f16x8 r;
    r[0] = (_Float16)(s * a[0]); r[1] = (_Float16)(s * a[1]);
    r[2] = (_Float16)(s * a[2]); r[3] = (_Float16)(s * a[3]);
    r[4] = (_Float16)(s * b[0]); r[5] = (_Float16)(s * b[1]);
    r[6] = (_Float16)(s * b[2]); r[7] = (_Float16)(s * b[3]);
    return r;
}

// ---------------------------------------------------------------------------
// GRU encoder — the measured optimum of the 6-structure design space
// (rounds 1-9): 128 blocks x 4 waves, swapped orientation (gates^T = W*x^T),
// wave w owns gate features 16w..16w+15 of r,z,n; h exchanged as packed-f16
// u32 pairs through LDS (b64 write, 2x b128 read); raw lgkm-only barrier so
// the depth-2 global x prefetch stays in flight across steps. Only delta vs
// the round-3 kernel (182 us): log2e folded into weights/biases, removing
// the exp-input multiplies from the serial gate chain.
// Lesson from R9 (kept): do NOT place next-step MFMA work ahead of the gate
// transcendentals in program order — in-order issue serializes it.
// ---------------------------------------------------------------------------
__global__ __launch_bounds__(256) void gru_kernel(
    const float* __restrict__ values, const float* __restrict__ mask,
    const int* __restrict__ seql, const float* __restrict__ eps,
    const float* __restrict__ W_ih, const float* __restrict__ W_hh,
    const float* __restrict__ b_ih, const float* __restrict__ b_hh,
    const float* __restrict__ W_z0, const float* __restrict__ b_z0,
    float* __restrict__ z0ws, float* __restrict__ parts)
{
    const int tid = threadIdx.x;
    const int w   = tid >> 6;
    const int l   = tid & 63;
    const int c   = l & 15;
    const int g4  = l >> 4;
    const int b0  = blockIdx.x * 16;

    __shared__ unsigned h_u32[2][16][36];   // packed f16 pairs [buf][batch][feat-pair]
    __shared__ float    zp_lds[16][65];
    __shared__ float    red_lds[4];

    for (int i = tid; i < 2 * 16 * 36; i += 256) (&h_u32[0][0][0])[i] = 0u;

    // Weight fragments, log2e-prescaled (r,z x log2e; n x 2*log2e).
    // lane (c,g4) holds W[gate*64 + 16w + c][kt*32 + 8g4 + i]
    f16x8 bih[3][2], bhh[3][2];
#pragma unroll
    for (int gate = 0; gate < 3; ++gate) {
        const float sc = (gate == 2) ? (2.0f * LOG2E) : LOG2E;
#pragma unroll
        for (int kt = 0; kt < 2; ++kt) {
            const float* p1 = W_ih + (gate * 64 + w * 16 + c) * 64 + kt * 32 + g4 * 8;
            bih[gate][kt] = pack8s(*(const f32x4*)p1, *(const f32x4*)(p1 + 4), sc);
            const float* p2 = W_hh + (gate * 64 + w * 16 + c) * 64 + kt * 32 + g4 * 8;
            bhh[gate][kt] = pack8s(*(const f32x4*)p2, *(const f32x4*)(p2 + 4), sc);
        }
    }

    // Per-reg bias vectors (same prescale): reg r <-> gate feature 16w+4g4+r
    f32x4 bRq, bZq, bNXq, bNHq;
#pragma unroll
    for (int r = 0; r < 4; ++r) {
        const int f = w * 16 + g4 * 4 + r;
        bRq[r]  = LOG2E * (b_ih[f]      + b_hh[f]);
        bZq[r]  = LOG2E * (b_ih[64 + f] + b_hh[64 + f]);
        bNXq[r] = 2.0f * LOG2E * b_ih[128 + f];
        bNHq[r] = 2.0f * LOG2E * b_hh[128 + f];
    }

    const int sl_c = seql[b0 + c];
    const int tmax = seql[b0];       // sorted descending -> block max
    float hp[4] = {0.f, 0.f, 0.f, 0.f};

    const float* vrow = values + (size_t)(b0 + c) * T_ * NV_ + g4 * 8;
    const float* mrow = mask   + (size_t)(b0 + c) * T_ * NV_ + g4 * 8;

    // depth-2 prefetch: named sets A (even t) and B (odd t)
    f32x4 av0, av1, am0, am1, bv0, bv1, bm0, bm1;
    {
        const float* vp = vrow + (T_ - 1) * NV_;
        const float* mp = mrow + (T_ - 1) * NV_;
        av0 = *(const f32x4*)vp; av1 = *(const f32x4*)(vp + 4);
        am0 = *(const f32x4*)mp; am1 = *(const f32x4*)(mp + 4);
    }
    {
        const int tt = (1 < tmax) ? 1 : 0;
        const float* vp = vrow + (T_ - 1 - tt) * NV_;
        const float* mp = mrow + (T_ - 1 - tt) * NV_;
        bv0 = *(const f32x4*)vp; bv1 = *(const f32x4*)(vp + 4);
        bm0 = *(const f32x4*)mp; bm1 = *(const f32x4*)(mp + 4);
    }

    __syncthreads();   // h zero-init visibility

    int cur = 0;

    auto STEP = [&](f32x4& v0, f32x4& v1, f32x4& m0, f32x4& m1, int tc) {
        // h B-fragment reads first; x-MFMAs cover their ~120cy latency
        f16x8 ha0 = *(const f16x8*)&h_u32[cur][c][4 * g4];
        f16x8 ha1 = *(const f16x8*)&h_u32[cur][c][16 + 4 * g4];

        f16x8 xa0 = pack8(v0, v1);   // vmcnt wait lands here (counted)
        f16x8 xa1 = pack8(m0, m1);

        // refill this set for t+2 (stays in flight across the raw barrier)
        const int tt = (tc + 2 < tmax) ? (tc + 2) : 0;
        const float* vp = vrow + (T_ - 1 - tt) * NV_;
        const float* mp = mrow + (T_ - 1 - tt) * NV_;
        v0 = *(const f32x4*)vp; v1 = *(const f32x4*)(vp + 4);
        m0 = *(const f32x4*)mp; m1 = *(const f32x4*)(mp + 4);

        // x-MFMAs first (independent of ds_read), then h-MFMAs R -> NH -> Z
        f32x4 accR  = MFMA16(bih[0][0], xa0, bRq);
        f32x4 accNX = MFMA16(bih[2][0], xa0, bNXq);
        f32x4 accZ  = MFMA16(bih[1][0], xa0, bZq);
        accR  = MFMA16(bih[0][1], xa1, accR);
        accNX = MFMA16(bih[2][1], xa1, accNX);
        accZ  = MFMA16(bih[1][1], xa1, accZ);

        f32x4 accNH = MFMA16(bhh[2][0], ha0, bNHq);
        accR  = MFMA16(bhh[0][0], ha0, accR);
        accNH = MFMA16(bhh[2][1], ha1, accNH);
        accR  = MFMA16(bhh[0][1], ha1, accR);
        accZ  = MFMA16(bhh[1][0], ha0, accZ);
        accZ  = MFMA16(bhh[1][1], ha1, accZ);

        const bool act = (tc < sl_c);
#pragma unroll
        for (int r = 0; r < 4; ++r) {
            float rr   = sigm2(accR[r]);
            float zz   = sigm2(accZ[r]);
            float nn   = tanh2(accNX[r] + rr * accNH[r]);
            float hnew = nn + zz * (hp[r] - nn);
            if (act) hp[r] = hnew;
        }

        const int nxt = cur ^ 1;
        f16x4 hq;
#pragma unroll
        for (int r = 0; r < 4; ++r) hq[r] = (_Float16)hp[r];
        *(f16x4*)&h_u32[nxt][c][8 * w + 2 * g4] = hq;   // single b64 store

        // raw barrier: drain LDS only; global prefetch stays outstanding
        asm volatile("s_waitcnt lgkmcnt(0)\n\ts_barrier" ::: "memory");
        cur = nxt;
    };

    int t = 0;
    while (true) {
        STEP(av0, av1, am0, am1, t);
        if (t + 1 >= tmax) break;
        STEP(bv0, bv1, bm0, bm1, t + 1);
        t += 2;
        if (t >= tmax) break;
    }

    // z0p^T = W_z0 * h^T + b_z0 : rows 16w+4g4+r, batch c
    f16x8 az0f[2];
#pragma unroll
    for (int kt = 0; kt < 2; ++kt) {
        const float* p = W_z0 + (w * 16 + c) * 64 + kt * 32 + g4 * 8;
        az0f[kt] = pack8(*(const f32x4*)p, *(const f32x4*)(p + 4));
    }
    f16x8 hf0 = *(const f16x8*)&h_u32[cur][c][4 * g4];
    f16x8 hf1 = *(const f16x8*)&h_u32[cur][c][16 + 4 * g4];
    f32x4 az;
#pragma unroll
    for (int r = 0; r < 4; ++r) az[r] = b_z0[w * 16 + g4 * 4 + r];
    az = MFMA16(az0f[0], hf0, az);
    az = MFMA16(az0f[1], hf1, az);
#pragma unroll
    for (int r = 0; r < 4; ++r) zp_lds[c][w * 16 + g4 * 4 + r] = az[r];
    __syncthreads();

    // z0 = mean + eps*exp(0.5*logvar); KL partial sum
    const int row = tid >> 4;
    const int j2  = (tid & 15) * 2;
    float m0 = zp_lds[row][j2],      m1 = zp_lds[row][j2 + 1];
    float v0 = zp_lds[row][32 + j2], v1 = zp_lds[row][32 + j2 + 1];
    const float* erow = eps + (size_t)(b0 + row) * L_;
    float e0 = erow[j2], e1 = erow[j2 + 1];
    float* zrow = z0ws + (size_t)(b0 + row) * L_;
    float s0 = __expf(0.5f * v0), s1 = __expf(0.5f * v1);
    zrow[j2]     = m0 + e0 * s0;
    zrow[j2 + 1] = m1 + e1 * s1;
    float kls = (1.0f + v0 - m0 * m0 - s0 * s0) + (1.0f + v1 - m1 * m1 - s1 * s1);
#pragma unroll
    for (int off = 32; off >= 1; off >>= 1) kls += __shfl_down(kls, off);
    if (l == 0) red_lds[w] = kls;
    __syncthreads();
    if (tid == 0) parts[blockIdx.x] = red_lds[0] + red_lds[1] + red_lds[2] + red_lds[3];
}

// ---------------------------------------------------------------------------
// ODE (RK4, NSTEP steps over [0,48]) + decoder; block 0 also finishes the KL.
// ---------------------------------------------------------------------------
__global__ __launch_bounds__(64) void ode_kernel(
    const float* __restrict__ z0ws, const float* __restrict__ parts,
    const float* __restrict__ oW1, const float* __restrict__ ob1,
    const float* __restrict__ oW2, const float* __restrict__ ob2,
    const float* __restrict__ oW3, const float* __restrict__ ob3,
    const float* __restrict__ dW1, const float* __restrict__ db1,
    const float* __restrict__ dW2, const float* __restrict__ db2,
    float* __restrict__ out)
{
    const int l  = threadIdx.x;
    const int c  = l & 15;
    const int g4 = l >> 4;
    const int b0 = blockIdx.x * 16;

    __shared__ _Float16 zbuf[16][40];
    __shared__ _Float16 buf1[16][72];
    __shared__ _Float16 buf2[16][72];

    f16x8 w1f[4], d1f[4], w2f[4][2], w3f[2][2];
#pragma unroll
    for (int mt = 0; mt < 4; ++mt) {
        const float* p = oW1 + (mt * 16 + c) * 32 + g4 * 8;
        w1f[mt] = pack8(*(const f32x4*)p, *(const f32x4*)(p + 4));
        const float* qq = dW1 + (mt * 16 + c) * 32 + g4 * 8;
        d1f[mt] = pack8(*(const f32x4*)qq, *(const f32x4*)(qq + 4));
#pragma unroll
        for (int kt = 0; kt < 2; ++kt) {
            const float* r = oW2 + (mt * 16 + c) * 64 + kt * 32 + g4 * 8;
            w2f[mt][kt] = pack8(*(const f32x4*)r, *(const f32x4*)(r + 4));
        }
    }
#pragma unroll
    for (int mt = 0; mt < 2; ++mt) {
#pragma unroll
        for (int kt = 0; kt < 2; ++kt) {
            const float* r = oW3 + (mt * 16 + c) * 64 + kt * 32 + g4 * 8;
            w3f[mt][kt] = pack8(*(const f32x4*)r, *(const f32x4*)(r + 4));
        }
    }

    f32x4 b1q[4], b2q[4], d1q[4], w2q[4], b3q[2];
#pragma unroll
    for (int mt = 0; mt < 4; ++mt) {
#pragma unroll
        for (int r = 0; r < 4; ++r) {
            b1q[mt][r] = ob1[mt * 16 + g4 * 4 + r];
            b2q[mt][r] = ob2[mt * 16 + g4 * 4 + r];
            d1q[mt][r] = db1[mt * 16 + g4 * 4 + r];
            w2q[mt][r] = dW2[mt * 16 + g4 * 4 + r];
        }
    }
#pragma unroll
    for (int mt = 0; mt < 2; ++mt) {
#pragma unroll
        for (int r = 0; r < 4; ++r) b3q[mt][r] = ob3[mt * 16 + g4 * 4 + r];
    }
    const float bd2 = db2[0];

    f32x4 z[2];
#pragma unroll
    for (int mt = 0; mt < 2; ++mt)
        z[mt] = *(const f32x4*)(z0ws + (size_t)(b0 + c) * L_ + mt * 16 + g4 * 4);

    auto evalf = [&](const f32x4* zin, f32x4* kout) {
#pragma unroll
        for (int mt = 0; mt < 2; ++mt) {
            f16x4 hv;
#pragma unroll
            for (int r = 0; r < 4; ++r) hv[r] = (_Float16)zin[mt][r];
            *(f16x4*)&zbuf[c][mt * 16 + g4 * 4] = hv;
        }
        f16x8 zf = *(const f16x8*)&zbuf[c][g4 * 8];

        f32x4 h1[4];
#pragma unroll
        for (int mt = 0; mt < 4; ++mt) h1[mt] = MFMA16(w1f[mt], zf, b1q[mt]);
#pragma unroll
        for (int mt = 0; mt < 4; ++mt) {
            f16x4 hv;
#pragma unroll
            for (int r = 0; r < 4; ++r) hv[r] = (_Float16)tanh_(h1[mt][r]);
            *(f16x4*)&buf1[c][mt * 16 + g4 * 4] = hv;
        }
        f16x8 a1 = *(const f16x8*)&buf1[c][g4 * 8];
        f16x8 a2 = *(const f16x8*)&buf1[c][32 + g4 * 8];

        f32x4 h2[4];
#pragma unroll
        for (int mt = 0; mt < 4; ++mt) {
            h2[mt] = MFMA16(w2f[mt][0], a1, b2q[mt]);
            h2[mt] = MFMA16(w2f[mt][1], a2, h2[mt]);
        }
#pragma unroll
        for (int mt = 0; mt < 4; ++mt) {
            f16x4 hv;
#pragma unroll
            for (int r = 0; r < 4; ++r) hv[r] = (_Float16)tanh_(h2[mt][r]);
            *(f16x4*)&buf2[c][mt * 16 + g4 * 4] = hv;
        }
        f16x8 a3 = *(const f16x8*)&buf2[c][g4 * 8];
        f16x8 a4 = *(const f16x8*)&buf2[c][32 + g4 * 8];

#pragma unroll
        for (int mt = 0; mt < 2; ++mt) {
            kout[mt] = MFMA16(w3f[mt][0], a3, b3q[mt]);
            kout[mt] = MFMA16(w3f[mt][1], a4, kout[mt]);
        }
    };

    const float dt = 48.0f / (float)NSTEP;
    for (int s = 0; s < NSTEP; ++s) {
        f32x4 k[2], ks[2], zt[2];
        evalf(z, k);
#pragma unroll
        for (int mt = 0; mt < 2; ++mt) { ks[mt] = k[mt]; zt[mt] = z[mt] + k[mt] * (0.5f * dt); }
        evalf(zt, k);
#pragma unroll
        for (int mt = 0; mt < 2; ++mt) { ks[mt] += k[mt] * 2.0f; zt[mt] = z[mt] + k[mt] * (0.5f * dt); }
        evalf(zt, k);
#pragma unroll
        for (int mt = 0; mt < 2; ++mt) { ks[mt] += k[mt] * 2.0f; zt[mt] = z[mt] + k[mt] * dt; }
        evalf(zt, k);
#pragma unroll
        for (int mt = 0; mt < 2; ++mt) z[mt] += (ks[mt] + k[mt]) * (dt / 6.0f);
    }

#pragma unroll
    for (int mt = 0; mt < 2; ++mt) {
        f16x4 hv;
#pragma unroll
        for (int r = 0; r < 4; ++r) hv[r] = (_Float16)z[mt][r];
        *(f16x4*)&zbuf[c][mt * 16 + g4 * 4] = hv;
    }
    f16x8 zf = *(const f16x8*)&zbuf[c][g4 * 8];
    float p = 0.0f;
#pragma unroll
    for (int mt = 0; mt < 4; ++mt) {
        f32x4 d = MFMA16(d1f[mt], zf, d1q[mt]);
#pragma unroll
        for (int r = 0; r < 4; ++r) p += fmaxf(d[r], 0.0f) * w2q[mt][r];
    }
    p += __shfl_xor(p, 16);
    p += __shfl_xor(p, 32);
    if (l < 16) out[b0 + c] = p + bd2;

    // KL finish (block 0): parts has 128 entries (one per gru block)
    if (blockIdx.x == 0) {
        float kp = parts[l] + parts[l + 64];
#pragma unroll
        for (int off = 32; off >= 1; off >>= 1) kp += __shfl_down(kp, off);
        if (l == 0) out[B_] = -0.5f * kp / (float)(B_ * L_);
    }
}

extern "C" void kernel_launch(void* const* d_in, const int* in_sizes, int n_in,
                              void* d_out, int out_size, void* d_ws, size_t ws_size,
                              hipStream_t stream) {
    const float* values = (const float*)d_in[1];
    const float* mask   = (const float*)d_in[2];
    const int*   seql   = (const int*)d_in[3];
    const float* eps    = (const float*)d_in[4];
    const float* W_ih   = (const float*)d_in[5];
    const float* W_hh   = (const float*)d_in[6];
    const float* b_ih   = (const float*)d_in[7];
    const float* b_hh   = (const float*)d_in[8];
    const float* W_z0   = (const float*)d_in[9];
    const float* b_z0   = (const float*)d_in[10];
    const float* oW1    = (const float*)d_in[11];
    const float* ob1    = (const float*)d_in[12];
    const float* oW2    = (const float*)d_in[13];
    const float* ob2    = (const float*)d_in[14];
    const float* oW3    = (const float*)d_in[15];
    const float* ob3    = (const float*)d_in[16];
    const float* dW1    = (const float*)d_in[17];
    const float* db1    = (const float*)d_in[18];
    const float* dW2    = (const float*)d_in[19];
    const float* db2    = (const float*)d_in[20];
    float* out = (float*)d_out;

    float* z0ws  = (float*)d_ws;
    float* parts = z0ws + (size_t)B_ * L_;

    hipLaunchKernelGGL(gru_kernel, dim3(B_ / 16), dim3(256), 0, stream,
                       values, mask, seql, eps, W_ih, W_hh, b_ih, b_hh, W_z0, b_z0,
                       z0ws, parts);
    hipLaunchKernelGGL(ode_kernel, dim3(B_ / 16), dim3(64), 0, stream,
                       z0ws, parts, oW1, ob1, oW2, ob2, oW3, ob3, dW1, db1, dW2, db2, out);
}

// Round 11
// 187.207 us; speedup vs baseline: 2.3758x; 1.0452x over previous
//
#include <hip/hip_runtime.h>

#define B_ 2048
#define T_ 256
#define NV_ 32
#define H_ 64
#define L_ 32
#define OH_ 64
#define NSTEP 12

typedef _Float16 f16x8 __attribute__((ext_vector_type(8)));
typedef _Float16 f16x4 __attribute__((ext_vector_type(4)));
typedef _Float16 f16x2 __attribute__((ext_vector_type(2)));
typedef float f32x4 __attribute__((ext_vector_type(4)));

#define MFMA16(a, b, c) __builtin_amdgcn_mfma_f32_16x16x32_f16((a), (b), (c), 0, 0, 0)

__device__ __forceinline__ float rcp_(float x) { return __builtin_amdgcn_rcpf(x); }
__device__ __forceinline__ float sigm(float x) { return rcp_(1.0f + __expf(-x)); }
__device__ __forceinline__ float tanh_(float x) { return 2.0f * rcp_(1.0f + __expf(-2.0f * x)) - 1.0f; }

__device__ __forceinline__ f16x8 pack8(f32x4 a, f32x4 b) {
    f16x8 r;
    r[0] = (_Float16)a[0]; r[1] = (_Float16)a[1]; r[2] = (_Float16)a[2]; r[3] = (_Float16)a[3];
    r[4] = (_Float16)b[0]; r[5] = (_Float16)b[1]; r[6] = (_Float16)b[2]; r[7] = (_Float16)b[3];
    return r;
}

// ---------------------------------------------------------------------------
// GRU encoder — exact round-3 structure, the measured optimum of the 7-point
// design space (R1-R10): 128 blocks x 4 waves, swapped orientation
// (gates^T = W * x^T), wave w owns gate features 16w..16w+15 of r,z,n,
// batch = lane&15. h exchanged as packed-f16 u32 pairs through LDS
// (2x b32 write, 2x b128 read); raw lgkm-only barrier keeps the depth-2
// global x prefetch in flight across steps.
//
// Measured floor: ~1706 cy/step. Structural constraint: every h feature
// feeds every gate, so each step requires a cross-wave LDS round-trip +
// barrier at ~1 wave/SIMD (nothing co-resident to hide latency); the
// sync-free alternative (sigma-permuted single-wave, R6) pays 4x MFMA issue
// and measured 2x worse. All pipes <10% busy -> latency-bound, not roofline.
// Deltas that measured WORSE and were reverted: producer/consumer split
// (+80cy), spin-flag sync (+250), 2-tile lockstep (+650), K-split/xp-hoist
// (+200), log2e-prescale + b64 store (+75).
// ---------------------------------------------------------------------------
__global__ __launch_bounds__(256) void gru_kernel(
    const float* __restrict__ values, const float* __restrict__ mask,
    const int* __restrict__ seql, const float* __restrict__ eps,
    const float* __restrict__ W_ih, const float* __restrict__ W_hh,
    const float* __restrict__ b_ih, const float* __restrict__ b_hh,
    const float* __restrict__ W_z0, const float* __restrict__ b_z0,
    float* __restrict__ z0ws, float* __restrict__ parts)
{
    const int tid = threadIdx.x;
    const int w   = tid >> 6;
    const int l   = tid & 63;
    const int c   = l & 15;
    const int g4  = l >> 4;
    const int b0  = blockIdx.x * 16;

    __shared__ unsigned h_u32[2][16][36];   // packed f16 pairs: [buf][batch][feat-pair]
    __shared__ float    zp_lds[16][65];
    __shared__ float    red_lds[4];

    for (int i = tid; i < 2 * 16 * 36; i += 256) (&h_u32[0][0][0])[i] = 0u;

    // Weight fragments: lane (c,g4) holds W[gate*64 + 16w + c][kt*32 + 8g4 + i]
    f16x8 bih[3][2], bhh[3][2];
#pragma unroll
    for (int gate = 0; gate < 3; ++gate) {
#pragma unroll
        for (int kt = 0; kt < 2; ++kt) {
            const float* p1 = W_ih + (gate * 64 + w * 16 + c) * 64 + kt * 32 + g4 * 8;
            bih[gate][kt] = pack8(*(const f32x4*)p1, *(const f32x4*)(p1 + 4));
            const float* p2 = W_hh + (gate * 64 + w * 16 + c) * 64 + kt * 32 + g4 * 8;
            bhh[gate][kt] = pack8(*(const f32x4*)p2, *(const f32x4*)(p2 + 4));
        }
    }

    // Per-reg bias vectors: reg r <-> gate feature f = 16w + 4g4 + r
    f32x4 bRq, bZq, bNXq, bNHq;
#pragma unroll
    for (int r = 0; r < 4; ++r) {
        const int f = w * 16 + g4 * 4 + r;
        bRq[r]  = b_ih[f]       + b_hh[f];
        bZq[r]  = b_ih[64 + f]  + b_hh[64 + f];
        bNXq[r] = b_ih[128 + f];
        bNHq[r] = b_hh[128 + f];
    }

    const int sl_c  = seql[b0 + c];   // batch = lane c for all 4 regs
    const int tmax  = seql[b0];       // sorted descending -> block max
    float hp[4] = {0.f, 0.f, 0.f, 0.f};

    const float* vrow = values + (size_t)(b0 + c) * T_ * NV_ + g4 * 8;
    const float* mrow = mask   + (size_t)(b0 + c) * T_ * NV_ + g4 * 8;

    // depth-2 prefetch: named sets A (even t) and B (odd t)
    f32x4 av0, av1, am0, am1, bv0, bv1, bm0, bm1;
    {
        const float* vp = vrow + (T_ - 1) * NV_;
        const float* mp = mrow + (T_ - 1) * NV_;
        av0 = *(const f32x4*)vp; av1 = *(const f32x4*)(vp + 4);
        am0 = *(const f32x4*)mp; am1 = *(const f32x4*)(mp + 4);
    }
    {
        const int tt = (1 < tmax) ? 1 : 0;
        const float* vp = vrow + (T_ - 1 - tt) * NV_;
        const float* mp = mrow + (T_ - 1 - tt) * NV_;
        bv0 = *(const f32x4*)vp; bv1 = *(const f32x4*)(vp + 4);
        bm0 = *(const f32x4*)mp; bm1 = *(const f32x4*)(mp + 4);
    }

    __syncthreads();   // h_u32 zero-init visibility

    int cur = 0;

    auto STEP = [&](f32x4& v0, f32x4& v1, f32x4& m0, f32x4& m1, int tc) {
        // h B-fragment read first (b128 x2); x-MFMAs cover its latency
        f16x8 ha0 = *(const f16x8*)&h_u32[cur][c][4 * g4];
        f16x8 ha1 = *(const f16x8*)&h_u32[cur][c][16 + 4 * g4];

        f16x8 xa0 = pack8(v0, v1);   // vmcnt wait (counted, ~complete)
        f16x8 xa1 = pack8(m0, m1);

        // refill this set for t+2 (stays in flight across the raw barrier)
        const int tt = (tc + 2 < tmax) ? (tc + 2) : 0;
        const float* vp = vrow + (T_ - 1 - tt) * NV_;
        const float* mp = mrow + (T_ - 1 - tt) * NV_;
        v0 = *(const f32x4*)vp; v1 = *(const f32x4*)(vp + 4);
        m0 = *(const f32x4*)mp; m1 = *(const f32x4*)(mp + 4);

        // x-MFMAs (independent of ds_read); then h-MFMAs R -> NH -> Z so the
        // sigmoid/tanh chain starts earliest
        f32x4 accR  = MFMA16(bih[0][0], xa0, bRq);
        f32x4 accNX = MFMA16(bih[2][0], xa0, bNXq);
        f32x4 accZ  = MFMA16(bih[1][0], xa0, bZq);
        accR  = MFMA16(bih[0][1], xa1, accR);
        accNX = MFMA16(bih[2][1], xa1, accNX);
        accZ  = MFMA16(bih[1][1], xa1, accZ);

        f32x4 accNH = MFMA16(bhh[2][0], ha0, bNHq);
        accR  = MFMA16(bhh[0][0], ha0, accR);
        accNH = MFMA16(bhh[2][1], ha1, accNH);
        accR  = MFMA16(bhh[0][1], ha1, accR);
        accZ  = MFMA16(bhh[1][0], ha0, accZ);
        accZ  = MFMA16(bhh[1][1], ha1, accZ);

        const bool act = (tc < sl_c);
#pragma unroll
        for (int r = 0; r < 4; ++r) {
            float rr   = sigm(accR[r]);
            float zz   = sigm(accZ[r]);
            float nn   = tanh_(accNX[r] + rr * accNH[r]);
            float hnew = nn + zz * (hp[r] - nn);
            if (act) hp[r] = hnew;
        }

        const int nxt = cur ^ 1;
        f16x2 q0 = { (_Float16)hp[0], (_Float16)hp[1] };
        f16x2 q1 = { (_Float16)hp[2], (_Float16)hp[3] };
        h_u32[nxt][c][8 * w + 2 * g4]     = __builtin_bit_cast(unsigned, q0);
        h_u32[nxt][c][8 * w + 2 * g4 + 1] = __builtin_bit_cast(unsigned, q1);

        // raw barrier: drain LDS only; global prefetch stays outstanding
        asm volatile("s_waitcnt lgkmcnt(0)\n\ts_barrier" ::: "memory");
        cur = nxt;
    };

    int t = 0;
    while (true) {
        STEP(av0, av1, am0, am1, t);
        if (t + 1 >= tmax) break;
        STEP(bv0, bv1, bm0, bm1, t + 1);
        t += 2;
        if (t >= tmax) break;
    }

    // z0p^T = W_z0 * h^T + b_z0 : rows 16w+4g4+r, batch c
    f16x8 az0f[2];
#pragma unroll
    for (int kt = 0; kt < 2; ++kt) {
        const float* p = W_z0 + (w * 16 + c) * 64 + kt * 32 + g4 * 8;
        az0f[kt] = pack8(*(const f32x4*)p, *(const f32x4*)(p + 4));
    }
    f16x8 hf0 = *(const f16x8*)&h_u32[cur][c][4 * g4];
    f16x8 hf1 = *(const f16x8*)&h_u32[cur][c][16 + 4 * g4];
    f32x4 az;
#pragma unroll
    for (int r = 0; r < 4; ++r) az[r] = b_z0[w * 16 + g4 * 4 + r];
    az = MFMA16(az0f[0], hf0, az);
    az = MFMA16(az0f[1], hf1, az);
#pragma unroll
    for (int r = 0; r < 4; ++r) zp_lds[c][w * 16 + g4 * 4 + r] = az[r];
    __syncthreads();

    // z0 = mean + eps*exp(0.5*logvar); KL partial sum
    const int row = tid >> 4;
    const int j2  = (tid & 15) * 2;
    float m0 = zp_lds[row][j2],      m1 = zp_lds[row][j2 + 1];
    float v0 = zp_lds[row][32 + j2], v1 = zp_lds[row][32 + j2 + 1];
    const float* erow = eps + (size_t)(b0 + row) * L_;
    float e0 = erow[j2], e1 = erow[j2 + 1];
    float* zrow = z0ws + (size_t)(b0 + row) * L_;
    float s0 = __expf(0.5f * v0), s1 = __expf(0.5f * v1);
    zrow[j2]     = m0 + e0 * s0;
    zrow[j2 + 1] = m1 + e1 * s1;
    float kls = (1.0f + v0 - m0 * m0 - s0 * s0) + (1.0f + v1 - m1 * m1 - s1 * s1);
#pragma unroll
    for (int off = 32; off >= 1; off >>= 1) kls += __shfl_down(kls, off);
    if (l == 0) red_lds[w] = kls;
    __syncthreads();
    if (tid == 0) parts[blockIdx.x] = red_lds[0] + red_lds[1] + red_lds[2] + red_lds[3];
}

// ---------------------------------------------------------------------------
// ODE (RK4, NSTEP steps over [0,48]) + decoder; block 0 also finishes the KL.
// ---------------------------------------------------------------------------
__global__ __launch_bounds__(64) void ode_kernel(
    const float* __restrict__ z0ws, const float* __restrict__ parts,
    const float* __restrict__ oW1, const float* __restrict__ ob1,
    const float* __restrict__ oW2, const float* __restrict__ ob2,
    const float* __restrict__ oW3, const float* __restrict__ ob3,
    const float* __restrict__ dW1, const float* __restrict__ db1,
    const float* __restrict__ dW2, const float* __restrict__ db2,
    float* __restrict__ out)
{
    const int l  = threadIdx.x;
    const int c  = l & 15;
    const int g4 = l >> 4;
    const int b0 = blockIdx.x * 16;

    __shared__ _Float16 zbuf[16][40];
    __shared__ _Float16 buf1[16][72];
    __shared__ _Float16 buf2[16][72];

    f16x8 w1f[4], d1f[4], w2f[4][2], w3f[2][2];
#pragma unroll
    for (int mt = 0; mt < 4; ++mt) {
        const float* p = oW1 + (mt * 16 + c) * 32 + g4 * 8;
        w1f[mt] = pack8(*(const f32x4*)p, *(const f32x4*)(p + 4));
        const float* qq = dW1 + (mt * 16 + c) * 32 + g4 * 8;
        d1f[mt] = pack8(*(const f32x4*)qq, *(const f32x4*)(qq + 4));
#pragma unroll
        for (int kt = 0; kt < 2; ++kt) {
            const float* r = oW2 + (mt * 16 + c) * 64 + kt * 32 + g4 * 8;
            w2f[mt][kt] = pack8(*(const f32x4*)r, *(const f32x4*)(r + 4));
        }
    }
#pragma unroll
    for (int mt = 0; mt < 2; ++mt) {
#pragma unroll
        for (int kt = 0; kt < 2; ++kt) {
            const float* r = oW3 + (mt * 16 + c) * 64 + kt * 32 + g4 * 8;
            w3f[mt][kt] = pack8(*(const f32x4*)r, *(const f32x4*)(r + 4));
        }
    }

    f32x4 b1q[4], b2q[4], d1q[4], w2q[4], b3q[2];
#pragma unroll
    for (int mt = 0; mt < 4; ++mt) {
#pragma unroll
        for (int r = 0; r < 4; ++r) {
            b1q[mt][r] = ob1[mt * 16 + g4 * 4 + r];
            b2q[mt][r] = ob2[mt * 16 + g4 * 4 + r];
            d1q[mt][r] = db1[mt * 16 + g4 * 4 + r];
            w2q[mt][r] = dW2[mt * 16 + g4 * 4 + r];
        }
    }
#pragma unroll
    for (int mt = 0; mt < 2; ++mt) {
#pragma unroll
        for (int r = 0; r < 4; ++r) b3q[mt][r] = ob3[mt * 16 + g4 * 4 + r];
    }
    const float bd2 = db2[0];

    f32x4 z[2];
#pragma unroll
    for (int mt = 0; mt < 2; ++mt)
        z[mt] = *(const f32x4*)(z0ws + (size_t)(b0 + c) * L_ + mt * 16 + g4 * 4);

    auto evalf = [&](const f32x4* zin, f32x4* kout) {
#pragma unroll
        for (int mt = 0; mt < 2; ++mt) {
            f16x4 hv;
#pragma unroll
            for (int r = 0; r < 4; ++r) hv[r] = (_Float16)zin[mt][r];
            *(f16x4*)&zbuf[c][mt * 16 + g4 * 4] = hv;
        }
        f16x8 zf = *(const f16x8*)&zbuf[c][g4 * 8];

        f32x4 h1[4];
#pragma unroll
        for (int mt = 0; mt < 4; ++mt) h1[mt] = MFMA16(w1f[mt], zf, b1q[mt]);
#pragma unroll
        for (int mt = 0; mt < 4; ++mt) {
            f16x4 hv;
#pragma unroll
            for (int r = 0; r < 4; ++r) hv[r] = (_Float16)tanh_(h1[mt][r]);
            *(f16x4*)&buf1[c][mt * 16 + g4 * 4] = hv;
        }
        f16x8 a1 = *(const f16x8*)&buf1[c][g4 * 8];
        f16x8 a2 = *(const f16x8*)&buf1[c][32 + g4 * 8];

        f32x4 h2[4];
#pragma unroll
        for (int mt = 0; mt < 4; ++mt) {
            h2[mt] = MFMA16(w2f[mt][0], a1, b2q[mt]);
            h2[mt] = MFMA16(w2f[mt][1], a2, h2[mt]);
        }
#pragma unroll
        for (int mt = 0; mt < 4; ++mt) {
            f16x4 hv;
#pragma unroll
            for (int r = 0; r < 4; ++r) hv[r] = (_Float16)tanh_(h2[mt][r]);
            *(f16x4*)&buf2[c][mt * 16 + g4 * 4] = hv;
        }
        f16x8 a3 = *(const f16x8*)&buf2[c][g4 * 8];
        f16x8 a4 = *(const f16x8*)&buf2[c][32 + g4 * 8];

#pragma unroll
        for (int mt = 0; mt < 2; ++mt) {
            kout[mt] = MFMA16(w3f[mt][0], a3, b3q[mt]);
            kout[mt] = MFMA16(w3f[mt][1], a4, kout[mt]);
        }
    };

    const float dt = 48.0f / (float)NSTEP;
    for (int s = 0; s < NSTEP; ++s) {
        f32x4 k[2], ks[2], zt[2];
        evalf(z, k);
#pragma unroll
        for (int mt = 0; mt < 2; ++mt) { ks[mt] = k[mt]; zt[mt] = z[mt] + k[mt] * (0.5f * dt); }
        evalf(zt, k);
#pragma unroll
        for (int mt = 0; mt < 2; ++mt) { ks[mt] += k[mt] * 2.0f; zt[mt] = z[mt] + k[mt] * (0.5f * dt); }
        evalf(zt, k);
#pragma unroll
        for (int mt = 0; mt < 2; ++mt) { ks[mt] += k[mt] * 2.0f; zt[mt] = z[mt] + k[mt] * dt; }
        evalf(zt, k);
#pragma unroll
        for (int mt = 0; mt < 2; ++mt) z[mt] += (ks[mt] + k[mt]) * (dt / 6.0f);
    }

#pragma unroll
    for (int mt = 0; mt < 2; ++mt) {
        f16x4 hv;
#pragma unroll
        for (int r = 0; r < 4; ++r) hv[r] = (_Float16)z[mt][r];
        *(f16x4*)&zbuf[c][mt * 16 + g4 * 4] = hv;
    }
    f16x8 zf = *(const f16x8*)&zbuf[c][g4 * 8];
    float p = 0.0f;
#pragma unroll
    for (int mt = 0; mt < 4; ++mt) {
        f32x4 d = MFMA16(d1f[mt], zf, d1q[mt]);
#pragma unroll
        for (int r = 0; r < 4; ++r) p += fmaxf(d[r], 0.0f) * w2q[mt][r];
    }
    p += __shfl_xor(p, 16);
    p += __shfl_xor(p, 32);
    if (l < 16) out[b0 + c] = p + bd2;

    // KL finish (block 0): parts has 128 entries (one per gru block)
    if (blockIdx.x == 0) {
        float kp = parts[l] + parts[l + 64];
#pragma unroll
        for (int off = 32; off >= 1; off >>= 1) kp += __shfl_down(kp, off);
        if (l == 0) out[B_] = -0.5f * kp / (float)(B_ * L_);
    }
}

extern "C" void kernel_launch(void* const* d_in, const int* in_sizes, int n_in,
                              void* d_out, int out_size, void* d_ws, size_t ws_size,
                              hipStream_t stream) {
    const float* values = (const float*)d_in[1];
    const float* mask   = (const float*)d_in[2];
    const int*   seql   = (const int*)d_in[3];
    const float* eps    = (const float*)d_in[4];
    const float* W_ih   = (const float*)d_in[5];
    const float* W_hh   = (const float*)d_in[6];
    const float* b_ih   = (const float*)d_in[7];
    const float* b_hh   = (const float*)d_in[8];
    const float* W_z0   = (const float*)d_in[9];
    const float* b_z0   = (const float*)d_in[10];
    const float* oW1    = (const float*)d_in[11];
    const float* ob1    = (const float*)d_in[12];
    const float* oW2    = (const float*)d_in[13];
    const float* ob2    = (const float*)d_in[14];
    const float* oW3    = (const float*)d_in[15];
    const float* ob3    = (const float*)d_in[16];
    const float* dW1    = (const float*)d_in[17];
    const float* db1    = (const float*)d_in[18];
    const float* dW2    = (const float*)d_in[19];
    const float* db2    = (const float*)d_in[20];
    float* out = (float*)d_out;

    float* z0ws  = (float*)d_ws;
    float* parts = z0ws + (size_t)B_ * L_;

    hipLaunchKernelGGL(gru_kernel, dim3(B_ / 16), dim3(256), 0, stream,
                       values, mask, seql, eps, W_ih, W_hh, b_ih, b_hh, W_z0, b_z0,
                       z0ws, parts);
    hipLaunchKernelGGL(ode_kernel, dim3(B_ / 16), dim3(64), 0, stream,
                       z0ws, parts, oW1, ob1, oW2, ob2, oW3, ob3, dW1, db1, dW2, db2, out);
}